// Round 6
// baseline (474.281 us; speedup 1.0000x reference)
//
#include <hip/hip_runtime.h>

typedef _Float16 half_t;
typedef _Float16 h8 __attribute__((ext_vector_type(8)));
typedef _Float16 h4 __attribute__((ext_vector_type(4)));
typedef float f4v __attribute__((ext_vector_type(4)));

// async global->LDS, 16B per lane; lds base must be wave-uniform (HW: base + lane*16)
__device__ __forceinline__ void async16(half_t* l, const half_t* g)
{
    __builtin_amdgcn_global_load_lds(
        (const __attribute__((address_space(1))) void*)g,
        (__attribute__((address_space(3))) void*)l,
        16, 0, 0);
}

// ---------------- prep: cast fp32->fp16 (mode 0) or cast+replicate-4 (mode 1) ----------------
struct PrepArgs {
    const float* src[15];
    half_t* dst[15];
    int n[15];
    int mode[15];
    int lg2[15];
};

__global__ __launch_bounds__(256) void prep_k(PrepArgs a)
{
    const int seg = blockIdx.y;
    const int i8 = (blockIdx.x * 256 + threadIdx.x) * 8;
    if (i8 >= a.n[seg]) return;
    const float* s = a.src[seg] + i8;
    f4v v0 = *(const f4v*)s;
    f4v v1 = *(const f4v*)(s + 4);
    h8 o;
    o[0] = (half_t)v0[0]; o[1] = (half_t)v0[1]; o[2] = (half_t)v0[2]; o[3] = (half_t)v0[3];
    o[4] = (half_t)v1[0]; o[5] = (half_t)v1[1]; o[6] = (half_t)v1[2]; o[7] = (half_t)v1[3];
    if (a.mode[seg] == 0) {
        *(h8*)(a.dst[seg] + i8) = o;
    } else {
        const int lg = a.lg2[seg], ch = 1 << lg;
        const int e = i8 >> lg, d = i8 & (ch - 1);
        half_t* base = a.dst[seg] + ((long long)e << (lg + 2)) + d;
        #pragma unroll
        for (int r = 0; r < 4; ++r) *(h8*)(base + r * ch) = o;
    }
}

// ---------------- staged tile load with row/k-limit masking ----------------
__device__ __forceinline__ h8 ldtile(const half_t* __restrict__ base, int row, int kb,
                                     int ld, int rowLim, int Klim)
{
    h8 v = {0, 0, 0, 0, 0, 0, 0, 0};
    if (row >= rowLim) return v;
    const half_t* p = base + (long long)row * ld + kb;
    if (kb + 8 <= Klim) return *(const h8*)p;
    #pragma unroll
    for (int e = 0; e < 8; ++e) if (kb + e < Klim) v[e] = p[e];
    return v;
}

// ---------------- batch descriptor, up to 6 heterogeneous jobs ----------------
struct BP {
    const half_t* A[6]; const half_t* B[6]; void* C[6];
    int Mlim[6], Nlim[6], Klim[6], nKt[6], lda[6], ldb[6], ldc[6];
    int divA[6]; long long sAhi[6], sAlo[6];
    int divB[6]; long long sBhi[6], sBlo[6];
    int divC[6]; long long sChi[6], sClo[6];
    int outMode[6];          // 1 = fp16 normal, 2 = fp16 transposed (coalesced runs)
    float alpha[6];
    int mT[6], nT[6];
    int cumEnd[5];
    int totW;
};

// ---------------- 64x64 MFMA GEMM (2 waves), fp32 normal out — out-proj ----------------
__global__ __launch_bounds__(128)
void gemm_b(BP P)
{
    __shared__ __align__(16) half_t SM[64 * 72];
    half_t (*As)[32] = (half_t(*)[32])SM;
    half_t (*Bs)[32] = (half_t(*)[32])(SM + 2048);

    int b = blockIdx.x;
    int s = 0, basev = 0;
    #pragma unroll
    for (int i = 0; i < 5; ++i) if (b >= P.cumEnd[i]) { s = i + 1; basev = P.cumEnd[i]; }
    b -= basev;
    const int mTl = P.mT[s], nTl = P.nT[s];
    const int mt = b % mTl;
    const int t2 = b / mTl;
    const int nt = t2 % nTl;
    const int z  = t2 / nTl;

    const half_t* A  = P.A[s] + (long long)(z / P.divA[s]) * P.sAhi[s] + (long long)(z % P.divA[s]) * P.sAlo[s];
    const half_t* Bp = P.B[s] + (long long)(z / P.divB[s]) * P.sBhi[s] + (long long)(z % P.divB[s]) * P.sBlo[s];
    const int Mlim = P.Mlim[s], Klim = P.Klim[s], nKt = P.nKt[s];
    const int lda = P.lda[s], ldb = P.ldb[s], ldc = P.ldc[s];
    const float alpha = P.alpha[s];
    const int m0 = mt * 64, n0 = nt * 64;
    const int tid = threadIdx.x;
    const int lane = tid & 63, w = tid >> 6;
    const int l15 = lane & 15, q = lane >> 4;

    const int r0 = tid >> 2, kg = tid & 3;
    const int r1 = r0 + 32;

    f4v acc[4][2];
    #pragma unroll
    for (int i = 0; i < 4; ++i)
        #pragma unroll
        for (int j = 0; j < 2; ++j) acc[i][j] = (f4v){0.f, 0.f, 0.f, 0.f};

    for (int kt = 0; kt < nKt; ++kt) {
        const int kb = kt * 32 + kg * 8;
        h8 a0 = ldtile(A, m0 + r0, kb, lda, Mlim, Klim);
        h8 a1 = ldtile(A, m0 + r1, kb, lda, Mlim, Klim);
        h8 b0 = ldtile(Bp, n0 + r0, kb, ldb, 1 << 30, Klim);
        h8 b1 = ldtile(Bp, n0 + r1, kb, ldb, 1 << 30, Klim);
        __syncthreads();
        *(h8*)&As[r0][kg * 8] = a0;
        *(h8*)&As[r1][kg * 8] = a1;
        *(h8*)&Bs[r0][kg * 8] = b0;
        *(h8*)&Bs[r1][kg * 8] = b1;
        __syncthreads();
        h8 af[4], bf[2];
        #pragma unroll
        for (int mti = 0; mti < 4; ++mti) af[mti] = *(h8*)&As[mti * 16 + l15][q * 8];
        #pragma unroll
        for (int nti = 0; nti < 2; ++nti) bf[nti] = *(h8*)&Bs[w * 32 + nti * 16 + l15][q * 8];
        #pragma unroll
        for (int mti = 0; mti < 4; ++mti)
            #pragma unroll
            for (int nti = 0; nti < 2; ++nti)
                acc[mti][nti] = __builtin_amdgcn_mfma_f32_16x16x32_f16(af[mti], bf[nti], acc[mti][nti], 0, 0, 0);
    }

    float* Cz = (float*)P.C[s] + (long long)(z / P.divC[s]) * P.sChi[s] + (long long)(z % P.divC[s]) * P.sClo[s];
    #pragma unroll
    for (int mti = 0; mti < 4; ++mti)
        #pragma unroll
        for (int r = 0; r < 4; ++r) {
            const int row = m0 + mti * 16 + q * 4 + r;
            if (row < Mlim) {
                #pragma unroll
                for (int nti = 0; nti < 2; ++nti) {
                    const int col = n0 + w * 32 + nti * 16 + l15;
                    Cz[(long long)row * ldc + col] = acc[mti][nti][r] * alpha;
                }
            }
        }
}

// ---------------- 128x128 MFMA GEMM (256 threads) — K/V/Q projections in ONE launch ----------------
// K-MAJOR LDS layout [kchunk q][row][8h]: wave wv stages kchunk wv (per-lane row = lane),
// fragment ds_read_b128 is 256B-contiguous per 16-lane group -> bank-conflict-free (was 8-way).
// 2-buffer double-buffered async staging; coalesced transpose epilogue.
__global__ __launch_bounds__(256, 3)
void gemm_w(BP P)
{
    __shared__ __align__(16) half_t SMEM[16384];    // 2 x 8192 halves dbuf; T2 overlay 128x128

    const int per = gridDim.x >> 3;
    int wk = (blockIdx.x & 7) * per + (blockIdx.x >> 3);
    if (wk >= P.totW) return;
    int s = 0, basev = 0;
    #pragma unroll
    for (int i = 0; i < 5; ++i) if (wk >= P.cumEnd[i]) { s = i + 1; basev = P.cumEnd[i]; }
    wk -= basev;
    const int mTl = P.mT[s], nTl = P.nT[s];
    const int mt = wk % mTl;
    const int t2 = wk / mTl;
    const int nt = t2 % nTl;
    const int z  = t2 / nTl;

    const half_t* A  = P.A[s] + (long long)(z / P.divA[s]) * P.sAhi[s] + (long long)(z % P.divA[s]) * P.sAlo[s];
    const half_t* Bp = P.B[s] + (long long)(z / P.divB[s]) * P.sBhi[s] + (long long)(z % P.divB[s]) * P.sBlo[s];
    const int Mlim = P.Mlim[s], Nlim = P.Nlim[s], nKt = P.nKt[s];
    const int lda = P.lda[s], ldb = P.ldb[s], ldc = P.ldc[s];
    const float alpha = P.alpha[s];
    const int m0 = mt * 128, n0 = nt * 128;
    const int tid = threadIdx.x;
    const int lane = tid & 63, wv = tid >> 6;
    const int wm = wv & 1, wn = wv >> 1;
    const int l15 = lane & 15, q = lane >> 4;

    // per-lane global rows (clamped; OOB rows duplicate last valid row, stores mask them);
    // wave wv stages k-chunk wv: col base = kt*32 + wv*8, advancing +32 per kt
    const int rA0 = min(m0 + lane,       Mlim - 1);
    const int rA1 = min(m0 + lane + 64,  Mlim - 1);
    const int rB0 = min(n0 + lane,       Nlim - 1);
    const int rB1 = min(n0 + lane + 64,  Nlim - 1);
    const half_t* gA0 = A  + (long long)rA0 * lda + wv * 8;
    const half_t* gA1 = A  + (long long)rA1 * lda + wv * 8;
    const half_t* gB0 = Bp + (long long)rB0 * ldb + wv * 8;
    const half_t* gB1 = Bp + (long long)rB1 * ldb + wv * 8;

    f4v acc[4][4];
    #pragma unroll
    for (int i = 0; i < 4; ++i)
        #pragma unroll
        for (int j = 0; j < 4; ++j) acc[i][j] = (f4v){0.f, 0.f, 0.f, 0.f};

    // buffer layout (halves): A = [q][128 rows][8] (4096), B likewise at +4096
    auto stage = [&](int off) {
        half_t* base = SMEM + off + wv * 1024;
        async16(base,               gA0);       // rows 0-63   of kchunk wv
        async16(base + 512,         gA1);       // rows 64-127
        async16(base + 4096,        gB0);
        async16(base + 4096 + 512,  gB1);
        gA0 += 32; gA1 += 32; gB0 += 32; gB1 += 32;
    };
    auto compute = [&](int off) {
        const half_t* Asb = SMEM + off + q * 1024;      // lane's kchunk
        const half_t* Bsb = Asb + 4096;
        h8 af[4], bf[4];
        #pragma unroll
        for (int mi = 0; mi < 4; ++mi) af[mi] = *(const h8*)(Asb + (wm * 64 + mi * 16 + l15) * 8);
        #pragma unroll
        for (int ni = 0; ni < 4; ++ni) bf[ni] = *(const h8*)(Bsb + (wn * 64 + ni * 16 + l15) * 8);
        #pragma unroll
        for (int mi = 0; mi < 4; ++mi)
            #pragma unroll
            for (int ni = 0; ni < 4; ++ni)
                acc[mi][ni] = __builtin_amdgcn_mfma_f32_16x16x32_f16(af[mi], bf[ni], acc[mi][ni], 0, 0, 0);
    };

    stage(0);
    __syncthreads();
    for (int kt = 0; kt < nKt; kt += 2) {
        stage(8192);
        compute(0);
        __syncthreads();
        if (kt + 2 < nKt) stage(0);
        compute(8192);
        __syncthreads();
    }

    if (P.outMode[s] == 1) {
        half_t* Cz = (half_t*)P.C[s] + (long long)(z / P.divC[s]) * P.sChi[s] + (long long)(z % P.divC[s]) * P.sClo[s];
        #pragma unroll
        for (int mi = 0; mi < 4; ++mi)
            #pragma unroll
            for (int r = 0; r < 4; ++r) {
                const int row = m0 + wm * 64 + mi * 16 + q * 4 + r;
                if (row < Mlim) {
                    #pragma unroll
                    for (int ni = 0; ni < 4; ++ni) {
                        const int col = n0 + wn * 64 + ni * 16 + l15;
                        if (col < Nlim) Cz[(long long)row * ldc + col] = (half_t)(acc[mi][ni][r] * alpha);
                    }
                }
            }
    } else {
        // coalesced transpose epilogue: C[col][m], ldc-padded rows; pad-writes are garbage
        // that downstream consumers never read meaningfully (zero-masked A-columns).
        // Single pass through overlay T2[128 cols][128 m], h4-granule XOR swizzle.
        half_t (*T2)[128] = (half_t(*)[128])SMEM;
        half_t* Cz = (half_t*)P.C[s] + (long long)(z / P.divC[s]) * P.sChi[s] + (long long)(z % P.divC[s]) * P.sClo[s];
        #pragma unroll
        for (int mi = 0; mi < 4; ++mi)
            #pragma unroll
            for (int ni = 0; ni < 4; ++ni) {
                h4 pk;
                #pragma unroll
                for (int r = 0; r < 4; ++r) pk[r] = (half_t)(acc[mi][ni][r] * alpha);
                const int col = wn * 64 + ni * 16 + l15;
                const int g   = wm * 16 + mi * 4 + q;               // m-group (4 halves)
                *(h4*)&T2[col][4 * (g ^ (col & 31))] = pk;
            }
        __syncthreads();
        {
            const int col  = tid >> 1;
            const int coff = (tid & 1) * 64;
            const int gb   = (tid & 1) * 16;
            const int mbase = m0 + coff;
            const int nfull = max(0, min(64, ldc - mbase)) >> 3;    // whole h8 runs in-row
            if (n0 + col < Nlim && nfull > 0) {
                half_t* rp = Cz + (long long)(n0 + col) * ldc + mbase;
                for (int j = 0; j < nfull; ++j) {
                    h4 lo = *(h4*)&T2[col][4 * ((gb + 2 * j)     ^ (col & 31))];
                    h4 hi = *(h4*)&T2[col][4 * ((gb + 2 * j + 1) ^ (col & 31))];
                    h8 v = {lo[0], lo[1], lo[2], lo[3], hi[0], hi[1], hi[2], hi[3]};
                    *(h8*)(rp + j * 8) = v;
                }
            }
        }
    }
}

// ---------------- scores: A-strip-resident GEMM + fused IN-stat partials ----------------
// B = KT[h][960][3200] (global-n rows, pad cols garbage — masked by zero A-columns).
// z enumerated h-major so co-XCD blocks share a head: their KT windows are adjacent
// column ranges of the SAME rows -> full line utilization, ~3 MB/XCD L2 footprint.
struct ScP {
    const half_t* Qt[4];
    const half_t* KT;
    half_t* C[4];
    float* Part[4];
    int Mlim[4];
    long long sA[4], sC[4];
    float alpha;
};

__global__ __launch_bounds__(256)
void gemm_s(ScP P)
{
    __shared__ __align__(16) half_t As[128][232];   // full-K strip (196 -> zero-pad)
    __shared__ __align__(16) half_t Bs[128][72];    // 64-wide B chunk
    __shared__ float red[8];

    const int per = gridDim.x >> 3;                 // 512/8 = 64 -> 8 z per XCD
    int wk = (blockIdx.x & 7) * per + (blockIdx.x >> 3);
    const int zl = wk >> 3, r = wk & 7;
    int s, mt;
    if (r < 1)      { s = 0; mt = 0; }
    else if (r < 2) { s = 1; mt = 0; }
    else if (r < 4) { s = 2; mt = r - 2; }
    else            { s = 3; mt = r - 4; }
    const int h = zl >> 4, b = zl & 15;             // h-major enumeration
    const int zq = b * 4 + h;                       // storage order of Qt/C/Part planes

    const half_t* A = P.Qt[s] + (long long)zq * P.sA[s] + (long long)mt * 128 * 208;
    const half_t* B = P.KT + (long long)h * 3072000 + (long long)b * 196;   // [960][3200] window
    const int rowLim = P.Mlim[s] - mt * 128;
    const float alpha = P.alpha;

    const int tid = threadIdx.x;
    const int lane = tid & 63, wv = tid >> 6;
    const int wm = wv & 1, wn = wv >> 1;
    const int l15 = lane & 15, q = lane >> 4;
    const int r0 = tid >> 2, kg = tid & 3;

    #pragma unroll
    for (int c = 0; c < 7; ++c) {
        const int kb = c * 32 + kg * 8;
        h8 a0 = ldtile(A, r0, kb, 208, rowLim, 196);
        h8 a1 = ldtile(A, r0 + 64, kb, 208, rowLim, 196);
        *(h8*)&As[r0][kb] = a0;
        *(h8*)&As[r0 + 64][kb] = a1;
    }

    half_t* Cz = P.C[s] + (long long)zq * P.sC[s] + (long long)mt * 128 * 960;
    float sv = 0.f, qq = 0.f;

    for (int nt = 0; nt < 8; ++nt) {
        f4v acc[4][4];
        #pragma unroll
        for (int i = 0; i < 4; ++i)
            #pragma unroll
            for (int j = 0; j < 4; ++j) acc[i][j] = (f4v){0.f, 0.f, 0.f, 0.f};

        const int j0 = nt * 128;
        #pragma unroll
        for (int c2 = 0; c2 < 4; ++c2) {
            h8 b00 = ldtile(B, j0 + r0,      c2 * 64 + kg * 8,      3200, 960, 196);
            h8 b01 = ldtile(B, j0 + r0,      c2 * 64 + 32 + kg * 8, 3200, 960, 196);
            h8 b10 = ldtile(B, j0 + r0 + 64, c2 * 64 + kg * 8,      3200, 960, 196);
            h8 b11 = ldtile(B, j0 + r0 + 64, c2 * 64 + 32 + kg * 8, 3200, 960, 196);
            __syncthreads();
            *(h8*)&Bs[r0][kg * 8] = b00;
            *(h8*)&Bs[r0][32 + kg * 8] = b01;
            *(h8*)&Bs[r0 + 64][kg * 8] = b10;
            *(h8*)&Bs[r0 + 64][32 + kg * 8] = b11;
            __syncthreads();
            const int nkk = (c2 < 3) ? 2 : 1;
            for (int kk = 0; kk < nkk; ++kk) {
                const int base = c2 * 64 + kk * 32;
                h8 af[4], bf[4];
                #pragma unroll
                for (int mi = 0; mi < 4; ++mi) af[mi] = *(h8*)&As[wm * 64 + mi * 16 + l15][base + q * 8];
                #pragma unroll
                for (int ni = 0; ni < 4; ++ni) bf[ni] = *(h8*)&Bs[wn * 64 + ni * 16 + l15][kk * 32 + q * 8];
                #pragma unroll
                for (int mi = 0; mi < 4; ++mi)
                    #pragma unroll
                    for (int ni = 0; ni < 4; ++ni)
                        acc[mi][ni] = __builtin_amdgcn_mfma_f32_16x16x32_f16(af[mi], bf[ni], acc[mi][ni], 0, 0, 0);
            }
        }
        #pragma unroll
        for (int mi = 0; mi < 4; ++mi)
            #pragma unroll
            for (int rr = 0; rr < 4; ++rr) {
                const int rowl = wm * 64 + mi * 16 + q * 4 + rr;
                #pragma unroll
                for (int ni = 0; ni < 4; ++ni) {
                    const int col = j0 + wn * 64 + ni * 16 + l15;
                    const float v = acc[mi][ni][rr] * alpha;
                    sv += v; qq += v * v;
                    if (rowl < rowLim && col < 960)
                        Cz[(long long)rowl * 960 + col] = (half_t)v;
                }
            }
    }

    #pragma unroll
    for (int o = 32; o > 0; o >>= 1) {
        sv += __shfl_down(sv, o, 64);
        qq += __shfl_down(qq, o, 64);
    }
    if (lane == 0) { red[wv] = sv; red[4 + wv] = qq; }
    __syncthreads();
    if (tid == 0) {
        float* PO = P.Part[s] + (long long)zq * 240 + mt * 2;
        PO[0] = red[0] + red[1] + red[2] + red[3];
        PO[1] = red[4] + red[5] + red[6] + red[7];
    }
}

// ---------------- ctx: fused IN-scale + exp + PV GEMM + denominator normalize ----------------
struct CtxP {
    const half_t* V;
    const half_t* S[4];
    half_t* C[4];
    const float* Part[4];
    int ch[4];
    int nPart[4];
    float pinv[4];
};

__global__ __launch_bounds__(256)
void ctx_k(CtxP P)
{
    __shared__ __align__(16) half_t As[128][40];
    __shared__ __align__(16) half_t Bs[128][40];
    __shared__ float denomP[128][4];
    __shared__ float denom[128];

    const int per = gridDim.x >> 3;                 // 1024/8 = 128 -> 8 z per XCD
    int wk = (blockIdx.x & 7) * per + (blockIdx.x >> 3);
    const int z = wk >> 4;
    const int r = wk & 15;
    int s, mt, nt;
    if (r < 2)      { s = 0; mt = r;            nt = 0; }
    else if (r < 4) { s = 1; mt = r - 2;        nt = 0; }
    else if (r < 8) { s = 2; mt = (r - 4) >> 1; nt = (r - 4) & 1; }
    else            { s = 3; mt = (r - 8) >> 2; nt = (r - 8) & 3; }
    const int b = z >> 2, h = z & 3;
    const int chS = P.ch[s];

    const float* part = P.Part[s] + (long long)z * 240;
    float Ssum = 0.f, Qsum = 0.f;
    for (int i = 0; i < P.nPart[s]; ++i) { Ssum += part[i * 2]; Qsum += part[i * 2 + 1]; }
    const float mn = Ssum * P.pinv[s];
    const float rs = rsqrtf(fmaxf(Qsum * P.pinv[s] - mn * mn, 0.f) + 1e-5f);

    const half_t* Av  = P.V + (long long)h * 3010560 + (long long)b * 188160;   // [196][960]
    const half_t* Bsc = P.S[s] + (long long)z * 960 * chS;                      // [ch][960] raw
    const int m0 = mt * 128, n0 = nt * 128;

    const int tid = threadIdx.x;
    const int lane = tid & 63, wv = tid >> 6;
    const int wm = wv & 1, wn = wv >> 1;
    const int l15 = lane & 15, q = lane >> 4;
    const int r0 = tid >> 2, kg = tid & 3;
    const int d0 = n0 + r0, d1 = n0 + r0 + 64;
    const bool ok0 = d0 < chS, ok1 = d1 < chS;

    f4v acc[4][4];
    #pragma unroll
    for (int i = 0; i < 4; ++i)
        #pragma unroll
        for (int j = 0; j < 4; ++j) acc[i][j] = (f4v){0.f, 0.f, 0.f, 0.f};

    float ds0 = 0.f, ds1 = 0.f;

    // prologue: loads for kt=0
    h8 a0n = ldtile(Av, m0 + r0, kg * 8, 960, 196, 960);
    h8 a1n = ldtile(Av, m0 + r0 + 64, kg * 8, 960, 196, 960);
    h8 s0n = {0,0,0,0,0,0,0,0}, s1n = {0,0,0,0,0,0,0,0};
    if (ok0) s0n = *(const h8*)(Bsc + (long long)d0 * 960 + kg * 8);
    if (ok1) s1n = *(const h8*)(Bsc + (long long)d1 * 960 + kg * 8);

    for (int kt = 0; kt < 30; ++kt) {
        h8 e0 = {0,0,0,0,0,0,0,0}, e1 = {0,0,0,0,0,0,0,0};
        if (ok0) {
            #pragma unroll
            for (int e = 0; e < 8; ++e) { float ev = __expf((float)s0n[e] * rs); ds0 += ev; e0[e] = (half_t)ev; }
        }
        if (ok1) {
            #pragma unroll
            for (int e = 0; e < 8; ++e) { float ev = __expf((float)s1n[e] * rs); ds1 += ev; e1[e] = (half_t)ev; }
        }
        h8 a0c = a0n, a1c = a1n;
        __syncthreads();
        *(h8*)&As[r0][kg * 8] = a0c;
        *(h8*)&As[r0 + 64][kg * 8] = a1c;
        *(h8*)&Bs[r0][kg * 8] = e0;
        *(h8*)&Bs[r0 + 64][kg * 8] = e1;
        __syncthreads();
        if (kt < 29) {
            const int kb = (kt + 1) * 32 + kg * 8;
            a0n = ldtile(Av, m0 + r0, kb, 960, 196, 960);
            a1n = ldtile(Av, m0 + r0 + 64, kb, 960, 196, 960);
            if (ok0) s0n = *(const h8*)(Bsc + (long long)d0 * 960 + kb);
            if (ok1) s1n = *(const h8*)(Bsc + (long long)d1 * 960 + kb);
        }
        h8 af[4], bf[4];
        #pragma unroll
        for (int mi = 0; mi < 4; ++mi) af[mi] = *(h8*)&As[wm * 64 + mi * 16 + l15][q * 8];
        #pragma unroll
        for (int ni = 0; ni < 4; ++ni) bf[ni] = *(h8*)&Bs[wn * 64 + ni * 16 + l15][q * 8];
        #pragma unroll
        for (int mi = 0; mi < 4; ++mi)
            #pragma unroll
            for (int ni = 0; ni < 4; ++ni)
                acc[mi][ni] = __builtin_amdgcn_mfma_f32_16x16x32_f16(af[mi], bf[ni], acc[mi][ni], 0, 0, 0);
    }

    denomP[r0][kg] = ds0;
    denomP[r0 + 64][kg] = ds1;
    __syncthreads();
    if (tid < 128) denom[tid] = denomP[tid][0] + denomP[tid][1] + denomP[tid][2] + denomP[tid][3];
    __syncthreads();

    half_t* Cz = P.C[s] + (long long)b * 784 * chS + (long long)h * chS;
    const int ldc = 4 * chS;
    #pragma unroll
    for (int ni = 0; ni < 4; ++ni) {
        const int coll = wn * 64 + ni * 16 + l15;
        const int col = n0 + coll;
        if (col < chS) {
            const float sc = 0.25f / denom[coll];
            #pragma unroll
            for (int mi = 0; mi < 4; ++mi)
                #pragma unroll
                for (int rr = 0; rr < 4; ++rr) {
                    const int row = m0 + wm * 64 + mi * 16 + q * 4 + rr;
                    if (row < 196)
                        Cz[(long long)row * ldc + col] = (half_t)(acc[mi][ni][rr] * sc);
                }
        }
    }
}

// ---------------- launcher ----------------
extern "C" void kernel_launch(void* const* d_in, const int* in_sizes, int n_in,
                              void* d_out, int out_size, void* d_ws, size_t ws_size,
                              hipStream_t stream)
{
    const float* emb[4]  = {(const float*)d_in[0], (const float*)d_in[1],
                            (const float*)d_in[2], (const float*)d_in[3]};
    const float* emb_all = (const float*)d_in[4];
    const float* Wq[4]   = {(const float*)d_in[5], (const float*)d_in[7],
                            (const float*)d_in[9], (const float*)d_in[11]};
    const float* Wo[4]   = {(const float*)d_in[6], (const float*)d_in[8],
                            (const float*)d_in[10], (const float*)d_in[12]};
    const float* Wk = (const float*)d_in[13];
    const float* Wv = (const float*)d_in[14];
    float* out = (float*)d_out;

    half_t* hb = (half_t*)d_ws;
    half_t* EAh = hb;                              // 3010560
    half_t* Eh  = EAh + 3010560;                   // 3010560
    half_t* Wkh = Eh  + 3010560;                   // 3686400
    half_t* Wvh = Wkh + 3686400;                   // 3686400
    half_t* Wqh = Wvh + 3686400;                   // 1392640
    half_t* Wo4 = Wqh + 1392640;                   // 1392640
    half_t* KT  = Wo4 + 1392640;                   // [h][960][3200]        = 12288000 (slot 12779520)
    half_t* Vh  = KT  + 12779520;                  // [h][3136][960]        = 12042240
    half_t* QtT = Vh  + 12042240;                  // per-scale [64][ch][208] = 12779520
    half_t* Ctx = QtT + 12779520;                  // per-scale [16][196][4ch] = 12042240
    half_t* Sch = Ctx + 12042240;                  // per-scale [64][ch][960] raw = 58982400
    float*  Part = (float*)(Sch + 58982400);       // 4 * 64 * 240 floats

    const int  chs[4]   = {64, 128, 256, 512};
    const int  lg2c[4]  = {6, 7, 8, 9};
    const long long offE[4]   = {0, 200704, 602112, 1404928};
    const long long offQ[4]   = {0, 16384, 81920, 344064};
    const long long offQt[4]  = {0, 851968, 2555904, 5963776};
    const long long offSc[4]  = {0, 3932160, 11796480, 27525120};
    const long long offCtx[4] = {0, 802816, 2408448, 5619712};
    const long long ooff[4]   = {0, 200704, 602112, 1404928};
    const float inv_sqrt_kv = 0.03227486121839514f;

    // ---- prep ----
    PrepArgs pa;
    pa.src[0] = emb_all; pa.dst[0] = EAh; pa.n[0] = 3010560; pa.mode[0] = 0; pa.lg2[0] = 0;
    for (int i = 0; i < 4; ++i) {
        pa.src[1 + i] = emb[i]; pa.dst[1 + i] = Eh + offE[i];
        pa.n[1 + i] = (int)(3136LL * chs[i]); pa.mode[1 + i] = 0; pa.lg2[1 + i] = 0;
    }
    pa.src[5] = Wk; pa.dst[5] = Wkh; pa.n[5] = 3686400; pa.mode[5] = 0; pa.lg2[5] = 0;
    pa.src[6] = Wv; pa.dst[6] = Wvh; pa.n[6] = 3686400; pa.mode[6] = 0; pa.lg2[6] = 0;
    for (int i = 0; i < 4; ++i) {
        pa.src[7 + i] = Wq[i]; pa.dst[7 + i] = Wqh + offQ[i];
        pa.n[7 + i] = 4 * chs[i] * chs[i]; pa.mode[7 + i] = 0; pa.lg2[7 + i] = 0;
        pa.src[11 + i] = Wo[i]; pa.dst[11 + i] = Wo4 + offQ[i];
        pa.n[11 + i] = chs[i] * chs[i]; pa.mode[11 + i] = 1; pa.lg2[11 + i] = lg2c[i];
    }
    prep_k<<<dim3(1800, 15), 256, 0, stream>>>(pa);

    // ---- K-proj + V-proj + Q-proj (all scales) in ONE 128x128 launch ----
    {
        BP p{};
        // slot 0: K projection -> KT[h][col j][n 3200] (transposed, coalesced runs)
        p.A[0] = EAh; p.B[0] = Wkh; p.C[0] = KT;
        p.Mlim[0] = 3136; p.Nlim[0] = 960; p.Klim[0] = 960; p.nKt[0] = 30;
        p.lda[0] = 960; p.ldb[0] = 960; p.ldc[0] = 3200;
        p.divA[0] = 1; p.sAhi[0] = 0; p.sAlo[0] = 0;
        p.divB[0] = 1; p.sBhi[0] = 921600; p.sBlo[0] = 0;
        p.divC[0] = 1; p.sChi[0] = 3072000; p.sClo[0] = 0;
        p.outMode[0] = 2; p.alpha[0] = 1.0f;
        p.mT[0] = 25; p.nT[0] = 8;
        // slot 1: V projection -> Vh[h][3136][960] (normal)
        p.A[1] = EAh; p.B[1] = Wvh; p.C[1] = Vh;
        p.Mlim[1] = 3136; p.Nlim[1] = 960; p.Klim[1] = 960; p.nKt[1] = 30;
        p.lda[1] = 960; p.ldb[1] = 960; p.ldc[1] = 960;
        p.divA[1] = 1; p.sAhi[1] = 0; p.sAlo[1] = 0;
        p.divB[1] = 1; p.sBhi[1] = 921600; p.sBlo[1] = 0;
        p.divC[1] = 1; p.sChi[1] = 3010560; p.sClo[1] = 0;
        p.outMode[1] = 1; p.alpha[1] = 1.0f;
        p.mT[1] = 25; p.nT[1] = 8;
        // slots 2..5: Q-proj per scale -> QtT[z][d][208] (transposed, coalesced runs)
        for (int i = 0; i < 4; ++i) {
            const int sl = 2 + i, ch = chs[i];
            p.A[sl] = Eh + offE[i]; p.B[sl] = Wqh + offQ[i]; p.C[sl] = QtT + offQt[i];
            p.Mlim[sl] = 196; p.Nlim[sl] = ch; p.Klim[sl] = ch; p.nKt[sl] = ch / 32;
            p.lda[sl] = ch; p.ldb[sl] = ch; p.ldc[sl] = 208;
            p.divA[sl] = 4; p.sAhi[sl] = 196LL * ch; p.sAlo[sl] = 0;
            p.divB[sl] = 4; p.sBhi[sl] = 0; p.sBlo[sl] = (long long)ch * ch;
            p.divC[sl] = 1; p.sChi[sl] = 208LL * ch; p.sClo[sl] = 0;
            p.outMode[sl] = 2; p.alpha[sl] = 1.0f;
            p.mT[sl] = 2; p.nT[sl] = (ch + 127) / 128;
        }
        int cum = 0;
        const int blocks[6] = {800, 800, 128, 128, 256, 512};
        for (int sl = 0; sl < 6; ++sl) { cum += blocks[sl]; if (sl < 5) p.cumEnd[sl] = cum; }
        p.totW = cum;                       // 2624, divisible by 8
        gemm_w<<<2624, 256, 0, stream>>>(p);
    }

    // ---- Scores (raw) + stats, strip-resident ----
    {
        ScP p{};
        for (int s = 0; s < 4; ++s) {
            p.Qt[s] = QtT + offQt[s];
            p.C[s] = Sch + offSc[s];
            p.Part[s] = Part + (long long)s * 64 * 240;
            p.Mlim[s] = chs[s];
            p.sA[s] = 208LL * chs[s];
            p.sC[s] = 960LL * chs[s];
        }
        p.KT = KT;
        p.alpha = inv_sqrt_kv;
        gemm_s<<<512, 256, 0, stream>>>(p);
    }

    // ---- ctx: fused exp/softmax + PV (pipelined) ----
    {
        CtxP p{};
        p.V = Vh;
        const int nP[4] = {1, 1, 2, 4};
        for (int s = 0; s < 4; ++s) {
            p.S[s] = Sch + offSc[s];
            p.C[s] = Ctx + offCtx[s];
            p.Part[s] = Part + (long long)s * 64 * 240;
            p.ch[s] = chs[s];
            p.nPart[s] = nP[s];
            p.pinv[s] = 1.0f / (chs[s] * 960);
        }
        ctx_k<<<1024, 256, 0, stream>>>(p);
    }

    // ---- out-proj, all scales: out fp32 = Ctx (196 x 4ch) x Wo4^T (64x64) ----
    {
        BP p{};
        int cum = 0;
        for (int s = 0; s < 4; ++s) {
            const int ch = chs[s];
            p.A[s] = Ctx + offCtx[s]; p.B[s] = Wo4 + offQ[s]; p.C[s] = out + ooff[s];
            p.Mlim[s] = 196; p.Nlim[s] = ch; p.Klim[s] = 4 * ch; p.nKt[s] = ch / 8;
            p.lda[s] = 4 * ch; p.ldb[s] = 4 * ch; p.ldc[s] = ch;
            p.divA[s] = 1; p.sAhi[s] = 784LL * ch; p.sAlo[s] = 0;
            p.divB[s] = 1; p.sBhi[s] = 0; p.sBlo[s] = 0;
            p.divC[s] = 1; p.sChi[s] = 196LL * ch; p.sClo[s] = 0;
            p.outMode[s] = 0; p.alpha[s] = 1.0f;
            p.mT[s] = 4; p.nT[s] = ch / 64;
            cum += 4 * (ch / 64) * 16;
            if (s < 3) p.cumEnd[s] = cum;
        }
        p.cumEnd[3] = p.cumEnd[4] = cum;
        p.totW = cum;
        gemm_b<<<960, 128, 0, stream>>>(p);
    }
}

// Round 7
// 463.176 us; speedup vs baseline: 1.0240x; 1.0240x over previous
//
#include <hip/hip_runtime.h>

typedef _Float16 half_t;
typedef _Float16 h8 __attribute__((ext_vector_type(8)));
typedef _Float16 h4 __attribute__((ext_vector_type(4)));
typedef float f4v __attribute__((ext_vector_type(4)));

// async global->LDS, 16B per lane; lds base must be wave-uniform (HW: base + lane*16)
__device__ __forceinline__ void async16(half_t* l, const half_t* g)
{
    __builtin_amdgcn_global_load_lds(
        (const __attribute__((address_space(1))) void*)g,
        (__attribute__((address_space(3))) void*)l,
        16, 0, 0);
}

// ---------------- prep: cast fp32->fp16 (mode 0) or cast+replicate-4 (mode 1) ----------------
struct PrepArgs {
    const float* src[15];
    half_t* dst[15];
    int n[15];
    int mode[15];
    int lg2[15];
};

__global__ __launch_bounds__(256) void prep_k(PrepArgs a)
{
    const int seg = blockIdx.y;
    const int i8 = (blockIdx.x * 256 + threadIdx.x) * 8;
    if (i8 >= a.n[seg]) return;
    const float* s = a.src[seg] + i8;
    f4v v0 = *(const f4v*)s;
    f4v v1 = *(const f4v*)(s + 4);
    h8 o;
    o[0] = (half_t)v0[0]; o[1] = (half_t)v0[1]; o[2] = (half_t)v0[2]; o[3] = (half_t)v0[3];
    o[4] = (half_t)v1[0]; o[5] = (half_t)v1[1]; o[6] = (half_t)v1[2]; o[7] = (half_t)v1[3];
    if (a.mode[seg] == 0) {
        *(h8*)(a.dst[seg] + i8) = o;
    } else {
        const int lg = a.lg2[seg], ch = 1 << lg;
        const int e = i8 >> lg, d = i8 & (ch - 1);
        half_t* base = a.dst[seg] + ((long long)e << (lg + 2)) + d;
        #pragma unroll
        for (int r = 0; r < 4; ++r) *(h8*)(base + r * ch) = o;
    }
}

// ---------------- staged tile load with row/k-limit masking ----------------
__device__ __forceinline__ h8 ldtile(const half_t* __restrict__ base, int row, int kb,
                                     int ld, int rowLim, int Klim)
{
    h8 v = {0, 0, 0, 0, 0, 0, 0, 0};
    if (row >= rowLim) return v;
    const half_t* p = base + (long long)row * ld + kb;
    if (kb + 8 <= Klim) return *(const h8*)p;
    #pragma unroll
    for (int e = 0; e < 8; ++e) if (kb + e < Klim) v[e] = p[e];
    return v;
}

// ---------------- batch descriptor, up to 6 heterogeneous jobs ----------------
struct BP {
    const half_t* A[6]; const half_t* B[6]; void* C[6];
    int Mlim[6], Nlim[6], Klim[6], nKt[6], lda[6], ldb[6], ldc[6];
    int divA[6]; long long sAhi[6], sAlo[6];
    int divB[6]; long long sBhi[6], sBlo[6];
    int divC[6]; long long sChi[6], sClo[6];
    int outMode[6];          // 1 = fp16 normal, 2 = fp16 transposed (coalesced runs)
    float alpha[6];
    int mT[6], nT[6];
    int cumEnd[5];
    int totW;
};

// ---------------- 64x64 MFMA GEMM (2 waves), fp32 normal out — out-proj ----------------
__global__ __launch_bounds__(128)
void gemm_b(BP P)
{
    __shared__ __align__(16) half_t SM[64 * 72];
    half_t (*As)[32] = (half_t(*)[32])SM;
    half_t (*Bs)[32] = (half_t(*)[32])(SM + 2048);

    int b = blockIdx.x;
    int s = 0, basev = 0;
    #pragma unroll
    for (int i = 0; i < 5; ++i) if (b >= P.cumEnd[i]) { s = i + 1; basev = P.cumEnd[i]; }
    b -= basev;
    const int mTl = P.mT[s], nTl = P.nT[s];
    const int mt = b % mTl;
    const int t2 = b / mTl;
    const int nt = t2 % nTl;
    const int z  = t2 / nTl;

    const half_t* A  = P.A[s] + (long long)(z / P.divA[s]) * P.sAhi[s] + (long long)(z % P.divA[s]) * P.sAlo[s];
    const half_t* Bp = P.B[s] + (long long)(z / P.divB[s]) * P.sBhi[s] + (long long)(z % P.divB[s]) * P.sBlo[s];
    const int Mlim = P.Mlim[s], Klim = P.Klim[s], nKt = P.nKt[s];
    const int lda = P.lda[s], ldb = P.ldb[s], ldc = P.ldc[s];
    const float alpha = P.alpha[s];
    const int m0 = mt * 64, n0 = nt * 64;
    const int tid = threadIdx.x;
    const int lane = tid & 63, w = tid >> 6;
    const int l15 = lane & 15, q = lane >> 4;

    const int r0 = tid >> 2, kg = tid & 3;
    const int r1 = r0 + 32;

    f4v acc[4][2];
    #pragma unroll
    for (int i = 0; i < 4; ++i)
        #pragma unroll
        for (int j = 0; j < 2; ++j) acc[i][j] = (f4v){0.f, 0.f, 0.f, 0.f};

    for (int kt = 0; kt < nKt; ++kt) {
        const int kb = kt * 32 + kg * 8;
        h8 a0 = ldtile(A, m0 + r0, kb, lda, Mlim, Klim);
        h8 a1 = ldtile(A, m0 + r1, kb, lda, Mlim, Klim);
        h8 b0 = ldtile(Bp, n0 + r0, kb, ldb, 1 << 30, Klim);
        h8 b1 = ldtile(Bp, n0 + r1, kb, ldb, 1 << 30, Klim);
        __syncthreads();
        *(h8*)&As[r0][kg * 8] = a0;
        *(h8*)&As[r1][kg * 8] = a1;
        *(h8*)&Bs[r0][kg * 8] = b0;
        *(h8*)&Bs[r1][kg * 8] = b1;
        __syncthreads();
        h8 af[4], bf[2];
        #pragma unroll
        for (int mti = 0; mti < 4; ++mti) af[mti] = *(h8*)&As[mti * 16 + l15][q * 8];
        #pragma unroll
        for (int nti = 0; nti < 2; ++nti) bf[nti] = *(h8*)&Bs[w * 32 + nti * 16 + l15][q * 8];
        #pragma unroll
        for (int mti = 0; mti < 4; ++mti)
            #pragma unroll
            for (int nti = 0; nti < 2; ++nti)
                acc[mti][nti] = __builtin_amdgcn_mfma_f32_16x16x32_f16(af[mti], bf[nti], acc[mti][nti], 0, 0, 0);
    }

    float* Cz = (float*)P.C[s] + (long long)(z / P.divC[s]) * P.sChi[s] + (long long)(z % P.divC[s]) * P.sClo[s];
    #pragma unroll
    for (int mti = 0; mti < 4; ++mti)
        #pragma unroll
        for (int r = 0; r < 4; ++r) {
            const int row = m0 + mti * 16 + q * 4 + r;
            if (row < Mlim) {
                #pragma unroll
                for (int nti = 0; nti < 2; ++nti) {
                    const int col = n0 + w * 32 + nti * 16 + l15;
                    Cz[(long long)row * ldc + col] = acc[mti][nti][r] * alpha;
                }
            }
        }
}

// ---------------- 128x128 MFMA GEMM (256 threads) — K/V/Q projections in ONE launch ----------------
// Both-sides-correct staging: lane = (kchunk<<4)|row16 -> global reads are 16 rows x 64B
// contiguous (coalesced, as rounds 0-4), and the linear LDS write produces per-16-row
// k-major blocks so fragment ds_read_b128 is contiguous 1KB per wave (conflict-free, as r6).
// LDS buffer: A = [g 0..7][kchunk 0..3][row16][8h] (4096h), B likewise at +4096.
__global__ __launch_bounds__(256, 3)
void gemm_w(BP P)
{
    __shared__ __align__(16) half_t SMEM[16384];    // 2 x 8192 halves dbuf; T2 overlay 128x128

    const int per = gridDim.x >> 3;
    int wk = (blockIdx.x & 7) * per + (blockIdx.x >> 3);
    if (wk >= P.totW) return;
    int s = 0, basev = 0;
    #pragma unroll
    for (int i = 0; i < 5; ++i) if (wk >= P.cumEnd[i]) { s = i + 1; basev = P.cumEnd[i]; }
    wk -= basev;
    const int mTl = P.mT[s], nTl = P.nT[s];
    const int mt = wk % mTl;
    const int t2 = wk / mTl;
    const int nt = t2 % nTl;
    const int z  = t2 / nTl;

    const half_t* A  = P.A[s] + (long long)(z / P.divA[s]) * P.sAhi[s] + (long long)(z % P.divA[s]) * P.sAlo[s];
    const half_t* Bp = P.B[s] + (long long)(z / P.divB[s]) * P.sBhi[s] + (long long)(z % P.divB[s]) * P.sBlo[s];
    const int Mlim = P.Mlim[s], Nlim = P.Nlim[s], nKt = P.nKt[s];
    const int lda = P.lda[s], ldb = P.ldb[s], ldc = P.ldc[s];
    const float alpha = P.alpha[s];
    const int m0 = mt * 128, n0 = nt * 128;
    const int tid = threadIdx.x;
    const int lane = tid & 63, wv = tid >> 6;
    const int wm = wv & 1, wn = wv >> 1;
    const int l15 = lane & 15, q = lane >> 4;

    // stage lane mapping: row-in-group = lane&15, kchunk = lane>>4
    // -> per wave-instruction: 16 rows x 64 contiguous bytes (coalesced)
    const int rA0 = min(m0 + wv * 16 + l15,       Mlim - 1);
    const int rA1 = min(m0 + 64 + wv * 16 + l15,  Mlim - 1);
    const int rB0 = min(n0 + wv * 16 + l15,       Nlim - 1);
    const int rB1 = min(n0 + 64 + wv * 16 + l15,  Nlim - 1);
    const half_t* gA0 = A  + (long long)rA0 * lda + q * 8;
    const half_t* gA1 = A  + (long long)rA1 * lda + q * 8;
    const half_t* gB0 = Bp + (long long)rB0 * ldb + q * 8;
    const half_t* gB1 = Bp + (long long)rB1 * ldb + q * 8;

    f4v acc[4][4];
    #pragma unroll
    for (int i = 0; i < 4; ++i)
        #pragma unroll
        for (int j = 0; j < 4; ++j) acc[i][j] = (f4v){0.f, 0.f, 0.f, 0.f};

    // wave wv writes g-blocks wv (rows m0+wv*16..) and 4+wv (rows m0+64+wv*16..); 512h each
    auto stage = [&](int off) {
        half_t* base = SMEM + off;
        async16(base + wv * 512,              gA0);
        async16(base + (4 + wv) * 512,        gA1);
        async16(base + 4096 + wv * 512,       gB0);
        async16(base + 4096 + (4 + wv) * 512, gB1);
        gA0 += 32; gA1 += 32; gB0 += 32; gB1 += 32;
    };
    // fragment read: g = wm*4+mi (A) / wn*4+ni (B); addr = g*512 + q*128 + l15*8
    // -> lane l reads bytes l*16..l*16+16 of one 1KB block: conflict-free
    auto compute = [&](int off) {
        const half_t* Asb = SMEM + off;
        const half_t* Bsb = Asb + 4096;
        h8 af[4], bf[4];
        #pragma unroll
        for (int mi = 0; mi < 4; ++mi) af[mi] = *(const h8*)(Asb + (wm * 4 + mi) * 512 + q * 128 + l15 * 8);
        #pragma unroll
        for (int ni = 0; ni < 4; ++ni) bf[ni] = *(const h8*)(Bsb + (wn * 4 + ni) * 512 + q * 128 + l15 * 8);
        #pragma unroll
        for (int mi = 0; mi < 4; ++mi)
            #pragma unroll
            for (int ni = 0; ni < 4; ++ni)
                acc[mi][ni] = __builtin_amdgcn_mfma_f32_16x16x32_f16(af[mi], bf[ni], acc[mi][ni], 0, 0, 0);
    };

    stage(0);
    __syncthreads();
    for (int kt = 0; kt < nKt; kt += 2) {
        stage(8192);
        compute(0);
        __syncthreads();
        if (kt + 2 < nKt) stage(0);
        compute(8192);
        __syncthreads();
    }

    if (P.outMode[s] == 1) {
        half_t* Cz = (half_t*)P.C[s] + (long long)(z / P.divC[s]) * P.sChi[s] + (long long)(z % P.divC[s]) * P.sClo[s];
        #pragma unroll
        for (int mi = 0; mi < 4; ++mi)
            #pragma unroll
            for (int r = 0; r < 4; ++r) {
                const int row = m0 + wm * 64 + mi * 16 + q * 4 + r;
                if (row < Mlim) {
                    #pragma unroll
                    for (int ni = 0; ni < 4; ++ni) {
                        const int col = n0 + wn * 64 + ni * 16 + l15;
                        if (col < Nlim) Cz[(long long)row * ldc + col] = (half_t)(acc[mi][ni][r] * alpha);
                    }
                }
            }
    } else {
        // coalesced transpose epilogue: C[col][m], ldc-padded rows; pad-writes are garbage
        // that downstream consumers never read meaningfully (zero-masked A-columns).
        // Single pass through overlay T2[128 cols][128 m], h4-granule XOR swizzle.
        half_t (*T2)[128] = (half_t(*)[128])SMEM;
        half_t* Cz = (half_t*)P.C[s] + (long long)(z / P.divC[s]) * P.sChi[s] + (long long)(z % P.divC[s]) * P.sClo[s];
        #pragma unroll
        for (int mi = 0; mi < 4; ++mi)
            #pragma unroll
            for (int ni = 0; ni < 4; ++ni) {
                h4 pk;
                #pragma unroll
                for (int r = 0; r < 4; ++r) pk[r] = (half_t)(acc[mi][ni][r] * alpha);
                const int col = wn * 64 + ni * 16 + l15;
                const int g   = wm * 16 + mi * 4 + q;               // m-group (4 halves)
                *(h4*)&T2[col][4 * (g ^ (col & 31))] = pk;
            }
        __syncthreads();
        {
            const int col  = tid >> 1;
            const int coff = (tid & 1) * 64;
            const int gb   = (tid & 1) * 16;
            const int mbase = m0 + coff;
            const int nfull = max(0, min(64, ldc - mbase)) >> 3;    // whole h8 runs in-row
            if (n0 + col < Nlim && nfull > 0) {
                half_t* rp = Cz + (long long)(n0 + col) * ldc + mbase;
                for (int j = 0; j < nfull; ++j) {
                    h4 lo = *(h4*)&T2[col][4 * ((gb + 2 * j)     ^ (col & 31))];
                    h4 hi = *(h4*)&T2[col][4 * ((gb + 2 * j + 1) ^ (col & 31))];
                    h8 v = {lo[0], lo[1], lo[2], lo[3], hi[0], hi[1], hi[2], hi[3]};
                    *(h8*)(rp + j * 8) = v;
                }
            }
        }
    }
}

// ---------------- scores: A-strip-resident GEMM + fused IN-stat partials ----------------
// B = KT[h][960][3200] (global-n rows, pad cols garbage — masked by zero A-columns).
// z enumerated h-major so co-XCD blocks share a head: their KT windows are adjacent
// column ranges of the SAME rows -> full line utilization, ~3 MB/XCD L2 footprint.
struct ScP {
    const half_t* Qt[4];
    const half_t* KT;
    half_t* C[4];
    float* Part[4];
    int Mlim[4];
    long long sA[4], sC[4];
    float alpha;
};

__global__ __launch_bounds__(256)
void gemm_s(ScP P)
{
    __shared__ __align__(16) half_t As[128][232];   // full-K strip (196 -> zero-pad)
    __shared__ __align__(16) half_t Bs[128][72];    // 64-wide B chunk
    __shared__ float red[8];

    const int per = gridDim.x >> 3;                 // 512/8 = 64 -> 8 z per XCD
    int wk = (blockIdx.x & 7) * per + (blockIdx.x >> 3);
    const int zl = wk >> 3, r = wk & 7;
    int s, mt;
    if (r < 1)      { s = 0; mt = 0; }
    else if (r < 2) { s = 1; mt = 0; }
    else if (r < 4) { s = 2; mt = r - 2; }
    else            { s = 3; mt = r - 4; }
    const int h = zl >> 4, b = zl & 15;             // h-major enumeration
    const int zq = b * 4 + h;                       // storage order of Qt/C/Part planes

    const half_t* A = P.Qt[s] + (long long)zq * P.sA[s] + (long long)mt * 128 * 208;
    const half_t* B = P.KT + (long long)h * 3072000 + (long long)b * 196;   // [960][3200] window
    const int rowLim = P.Mlim[s] - mt * 128;
    const float alpha = P.alpha;

    const int tid = threadIdx.x;
    const int lane = tid & 63, wv = tid >> 6;
    const int wm = wv & 1, wn = wv >> 1;
    const int l15 = lane & 15, q = lane >> 4;
    const int r0 = tid >> 2, kg = tid & 3;

    #pragma unroll
    for (int c = 0; c < 7; ++c) {
        const int kb = c * 32 + kg * 8;
        h8 a0 = ldtile(A, r0, kb, 208, rowLim, 196);
        h8 a1 = ldtile(A, r0 + 64, kb, 208, rowLim, 196);
        *(h8*)&As[r0][kb] = a0;
        *(h8*)&As[r0 + 64][kb] = a1;
    }

    half_t* Cz = P.C[s] + (long long)zq * P.sC[s] + (long long)mt * 128 * 960;
    float sv = 0.f, qq = 0.f;

    for (int nt = 0; nt < 8; ++nt) {
        f4v acc[4][4];
        #pragma unroll
        for (int i = 0; i < 4; ++i)
            #pragma unroll
            for (int j = 0; j < 4; ++j) acc[i][j] = (f4v){0.f, 0.f, 0.f, 0.f};

        const int j0 = nt * 128;
        #pragma unroll
        for (int c2 = 0; c2 < 4; ++c2) {
            h8 b00 = ldtile(B, j0 + r0,      c2 * 64 + kg * 8,      3200, 960, 196);
            h8 b01 = ldtile(B, j0 + r0,      c2 * 64 + 32 + kg * 8, 3200, 960, 196);
            h8 b10 = ldtile(B, j0 + r0 + 64, c2 * 64 + kg * 8,      3200, 960, 196);
            h8 b11 = ldtile(B, j0 + r0 + 64, c2 * 64 + 32 + kg * 8, 3200, 960, 196);
            __syncthreads();
            *(h8*)&Bs[r0][kg * 8] = b00;
            *(h8*)&Bs[r0][32 + kg * 8] = b01;
            *(h8*)&Bs[r0 + 64][kg * 8] = b10;
            *(h8*)&Bs[r0 + 64][32 + kg * 8] = b11;
            __syncthreads();
            const int nkk = (c2 < 3) ? 2 : 1;
            for (int kk = 0; kk < nkk; ++kk) {
                const int base = c2 * 64 + kk * 32;
                h8 af[4], bf[4];
                #pragma unroll
                for (int mi = 0; mi < 4; ++mi) af[mi] = *(h8*)&As[wm * 64 + mi * 16 + l15][base + q * 8];
                #pragma unroll
                for (int ni = 0; ni < 4; ++ni) bf[ni] = *(h8*)&Bs[wn * 64 + ni * 16 + l15][kk * 32 + q * 8];
                #pragma unroll
                for (int mi = 0; mi < 4; ++mi)
                    #pragma unroll
                    for (int ni = 0; ni < 4; ++ni)
                        acc[mi][ni] = __builtin_amdgcn_mfma_f32_16x16x32_f16(af[mi], bf[ni], acc[mi][ni], 0, 0, 0);
            }
        }
        #pragma unroll
        for (int mi = 0; mi < 4; ++mi)
            #pragma unroll
            for (int rr = 0; rr < 4; ++rr) {
                const int rowl = wm * 64 + mi * 16 + q * 4 + rr;
                #pragma unroll
                for (int ni = 0; ni < 4; ++ni) {
                    const int col = j0 + wn * 64 + ni * 16 + l15;
                    const float v = acc[mi][ni][rr] * alpha;
                    sv += v; qq += v * v;
                    if (rowl < rowLim && col < 960)
                        Cz[(long long)rowl * 960 + col] = (half_t)v;
                }
            }
    }

    #pragma unroll
    for (int o = 32; o > 0; o >>= 1) {
        sv += __shfl_down(sv, o, 64);
        qq += __shfl_down(qq, o, 64);
    }
    if (lane == 0) { red[wv] = sv; red[4 + wv] = qq; }
    __syncthreads();
    if (tid == 0) {
        float* PO = P.Part[s] + (long long)zq * 240 + mt * 2;
        PO[0] = red[0] + red[1] + red[2] + red[3];
        PO[1] = red[4] + red[5] + red[6] + red[7];
    }
}

// ---------------- ctx: fused IN-scale + exp + PV GEMM + denominator normalize ----------------
struct CtxP {
    const half_t* V;
    const half_t* S[4];
    half_t* C[4];
    const float* Part[4];
    int ch[4];
    int nPart[4];
    float pinv[4];
};

__global__ __launch_bounds__(256)
void ctx_k(CtxP P)
{
    __shared__ __align__(16) half_t As[128][40];
    __shared__ __align__(16) half_t Bs[128][40];
    __shared__ float denomP[128][4];
    __shared__ float denom[128];

    const int per = gridDim.x >> 3;                 // 1024/8 = 128 -> 8 z per XCD
    int wk = (blockIdx.x & 7) * per + (blockIdx.x >> 3);
    const int z = wk >> 4;
    const int r = wk & 15;
    int s, mt, nt;
    if (r < 2)      { s = 0; mt = r;            nt = 0; }
    else if (r < 4) { s = 1; mt = r - 2;        nt = 0; }
    else if (r < 8) { s = 2; mt = (r - 4) >> 1; nt = (r - 4) & 1; }
    else            { s = 3; mt = (r - 8) >> 2; nt = (r - 8) & 3; }
    const int b = z >> 2, h = z & 3;
    const int chS = P.ch[s];

    const float* part = P.Part[s] + (long long)z * 240;
    float Ssum = 0.f, Qsum = 0.f;
    for (int i = 0; i < P.nPart[s]; ++i) { Ssum += part[i * 2]; Qsum += part[i * 2 + 1]; }
    const float mn = Ssum * P.pinv[s];
    const float rs = rsqrtf(fmaxf(Qsum * P.pinv[s] - mn * mn, 0.f) + 1e-5f);

    const half_t* Av  = P.V + (long long)h * 3010560 + (long long)b * 188160;   // [196][960]
    const half_t* Bsc = P.S[s] + (long long)z * 960 * chS;                      // [ch][960] raw
    const int m0 = mt * 128, n0 = nt * 128;

    const int tid = threadIdx.x;
    const int lane = tid & 63, wv = tid >> 6;
    const int wm = wv & 1, wn = wv >> 1;
    const int l15 = lane & 15, q = lane >> 4;
    const int r0 = tid >> 2, kg = tid & 3;
    const int d0 = n0 + r0, d1 = n0 + r0 + 64;
    const bool ok0 = d0 < chS, ok1 = d1 < chS;

    f4v acc[4][4];
    #pragma unroll
    for (int i = 0; i < 4; ++i)
        #pragma unroll
        for (int j = 0; j < 4; ++j) acc[i][j] = (f4v){0.f, 0.f, 0.f, 0.f};

    float ds0 = 0.f, ds1 = 0.f;

    // prologue: loads for kt=0
    h8 a0n = ldtile(Av, m0 + r0, kg * 8, 960, 196, 960);
    h8 a1n = ldtile(Av, m0 + r0 + 64, kg * 8, 960, 196, 960);
    h8 s0n = {0,0,0,0,0,0,0,0}, s1n = {0,0,0,0,0,0,0,0};
    if (ok0) s0n = *(const h8*)(Bsc + (long long)d0 * 960 + kg * 8);
    if (ok1) s1n = *(const h8*)(Bsc + (long long)d1 * 960 + kg * 8);

    for (int kt = 0; kt < 30; ++kt) {
        h8 e0 = {0,0,0,0,0,0,0,0}, e1 = {0,0,0,0,0,0,0,0};
        if (ok0) {
            #pragma unroll
            for (int e = 0; e < 8; ++e) { float ev = __expf((float)s0n[e] * rs); ds0 += ev; e0[e] = (half_t)ev; }
        }
        if (ok1) {
            #pragma unroll
            for (int e = 0; e < 8; ++e) { float ev = __expf((float)s1n[e] * rs); ds1 += ev; e1[e] = (half_t)ev; }
        }
        h8 a0c = a0n, a1c = a1n;
        __syncthreads();
        *(h8*)&As[r0][kg * 8] = a0c;
        *(h8*)&As[r0 + 64][kg * 8] = a1c;
        *(h8*)&Bs[r0][kg * 8] = e0;
        *(h8*)&Bs[r0 + 64][kg * 8] = e1;
        __syncthreads();
        if (kt < 29) {
            const int kb = (kt + 1) * 32 + kg * 8;
            a0n = ldtile(Av, m0 + r0, kb, 960, 196, 960);
            a1n = ldtile(Av, m0 + r0 + 64, kb, 960, 196, 960);
            if (ok0) s0n = *(const h8*)(Bsc + (long long)d0 * 960 + kb);
            if (ok1) s1n = *(const h8*)(Bsc + (long long)d1 * 960 + kb);
        }
        h8 af[4], bf[4];
        #pragma unroll
        for (int mi = 0; mi < 4; ++mi) af[mi] = *(h8*)&As[wm * 64 + mi * 16 + l15][q * 8];
        #pragma unroll
        for (int ni = 0; ni < 4; ++ni) bf[ni] = *(h8*)&Bs[wn * 64 + ni * 16 + l15][q * 8];
        #pragma unroll
        for (int mi = 0; mi < 4; ++mi)
            #pragma unroll
            for (int ni = 0; ni < 4; ++ni)
                acc[mi][ni] = __builtin_amdgcn_mfma_f32_16x16x32_f16(af[mi], bf[ni], acc[mi][ni], 0, 0, 0);
    }

    denomP[r0][kg] = ds0;
    denomP[r0 + 64][kg] = ds1;
    __syncthreads();
    if (tid < 128) denom[tid] = denomP[tid][0] + denomP[tid][1] + denomP[tid][2] + denomP[tid][3];
    __syncthreads();

    half_t* Cz = P.C[s] + (long long)b * 784 * chS + (long long)h * chS;
    const int ldc = 4 * chS;
    #pragma unroll
    for (int ni = 0; ni < 4; ++ni) {
        const int coll = wn * 64 + ni * 16 + l15;
        const int col = n0 + coll;
        if (col < chS) {
            const float sc = 0.25f / denom[coll];
            #pragma unroll
            for (int mi = 0; mi < 4; ++mi)
                #pragma unroll
                for (int rr = 0; rr < 4; ++rr) {
                    const int row = m0 + wm * 64 + mi * 16 + q * 4 + rr;
                    if (row < 196)
                        Cz[(long long)row * ldc + col] = (half_t)(acc[mi][ni][rr] * sc);
                }
        }
    }
}

// ---------------- launcher ----------------
extern "C" void kernel_launch(void* const* d_in, const int* in_sizes, int n_in,
                              void* d_out, int out_size, void* d_ws, size_t ws_size,
                              hipStream_t stream)
{
    const float* emb[4]  = {(const float*)d_in[0], (const float*)d_in[1],
                            (const float*)d_in[2], (const float*)d_in[3]};
    const float* emb_all = (const float*)d_in[4];
    const float* Wq[4]   = {(const float*)d_in[5], (const float*)d_in[7],
                            (const float*)d_in[9], (const float*)d_in[11]};
    const float* Wo[4]   = {(const float*)d_in[6], (const float*)d_in[8],
                            (const float*)d_in[10], (const float*)d_in[12]};
    const float* Wk = (const float*)d_in[13];
    const float* Wv = (const float*)d_in[14];
    float* out = (float*)d_out;

    half_t* hb = (half_t*)d_ws;
    half_t* EAh = hb;                              // 3010560
    half_t* Eh  = EAh + 3010560;                   // 3010560
    half_t* Wkh = Eh  + 3010560;                   // 3686400
    half_t* Wvh = Wkh + 3686400;                   // 3686400
    half_t* Wqh = Wvh + 3686400;                   // 1392640
    half_t* Wo4 = Wqh + 1392640;                   // 1392640
    half_t* KT  = Wo4 + 1392640;                   // [h][960][3200]        = 12288000 (slot 12779520)
    half_t* Vh  = KT  + 12779520;                  // [h][3136][960]        = 12042240
    half_t* QtT = Vh  + 12042240;                  // per-scale [64][ch][208] = 12779520
    half_t* Ctx = QtT + 12779520;                  // per-scale [16][196][4ch] = 12042240
    half_t* Sch = Ctx + 12042240;                  // per-scale [64][ch][960] raw = 58982400
    float*  Part = (float*)(Sch + 58982400);       // 4 * 64 * 240 floats

    const int  chs[4]   = {64, 128, 256, 512};
    const int  lg2c[4]  = {6, 7, 8, 9};
    const long long offE[4]   = {0, 200704, 602112, 1404928};
    const long long offQ[4]   = {0, 16384, 81920, 344064};
    const long long offQt[4]  = {0, 851968, 2555904, 5963776};
    const long long offSc[4]  = {0, 3932160, 11796480, 27525120};
    const long long offCtx[4] = {0, 802816, 2408448, 5619712};
    const long long ooff[4]   = {0, 200704, 602112, 1404928};
    const float inv_sqrt_kv = 0.03227486121839514f;

    // ---- prep ----
    PrepArgs pa;
    pa.src[0] = emb_all; pa.dst[0] = EAh; pa.n[0] = 3010560; pa.mode[0] = 0; pa.lg2[0] = 0;
    for (int i = 0; i < 4; ++i) {
        pa.src[1 + i] = emb[i]; pa.dst[1 + i] = Eh + offE[i];
        pa.n[1 + i] = (int)(3136LL * chs[i]); pa.mode[1 + i] = 0; pa.lg2[1 + i] = 0;
    }
    pa.src[5] = Wk; pa.dst[5] = Wkh; pa.n[5] = 3686400; pa.mode[5] = 0; pa.lg2[5] = 0;
    pa.src[6] = Wv; pa.dst[6] = Wvh; pa.n[6] = 3686400; pa.mode[6] = 0; pa.lg2[6] = 0;
    for (int i = 0; i < 4; ++i) {
        pa.src[7 + i] = Wq[i]; pa.dst[7 + i] = Wqh + offQ[i];
        pa.n[7 + i] = 4 * chs[i] * chs[i]; pa.mode[7 + i] = 0; pa.lg2[7 + i] = 0;
        pa.src[11 + i] = Wo[i]; pa.dst[11 + i] = Wo4 + offQ[i];
        pa.n[11 + i] = chs[i] * chs[i]; pa.mode[11 + i] = 1; pa.lg2[11 + i] = lg2c[i];
    }
    prep_k<<<dim3(1800, 15), 256, 0, stream>>>(pa);

    // ---- K-proj + V-proj + Q-proj (all scales) in ONE 128x128 launch ----
    {
        BP p{};
        // slot 0: K projection -> KT[h][col j][n 3200] (transposed, coalesced runs)
        p.A[0] = EAh; p.B[0] = Wkh; p.C[0] = KT;
        p.Mlim[0] = 3136; p.Nlim[0] = 960; p.Klim[0] = 960; p.nKt[0] = 30;
        p.lda[0] = 960; p.ldb[0] = 960; p.ldc[0] = 3200;
        p.divA[0] = 1; p.sAhi[0] = 0; p.sAlo[0] = 0;
        p.divB[0] = 1; p.sBhi[0] = 921600; p.sBlo[0] = 0;
        p.divC[0] = 1; p.sChi[0] = 3072000; p.sClo[0] = 0;
        p.outMode[0] = 2; p.alpha[0] = 1.0f;
        p.mT[0] = 25; p.nT[0] = 8;
        // slot 1: V projection -> Vh[h][3136][960] (normal)
        p.A[1] = EAh; p.B[1] = Wvh; p.C[1] = Vh;
        p.Mlim[1] = 3136; p.Nlim[1] = 960; p.Klim[1] = 960; p.nKt[1] = 30;
        p.lda[1] = 960; p.ldb[1] = 960; p.ldc[1] = 960;
        p.divA[1] = 1; p.sAhi[1] = 0; p.sAlo[1] = 0;
        p.divB[1] = 1; p.sBhi[1] = 921600; p.sBlo[1] = 0;
        p.divC[1] = 1; p.sChi[1] = 3010560; p.sClo[1] = 0;
        p.outMode[1] = 1; p.alpha[1] = 1.0f;
        p.mT[1] = 25; p.nT[1] = 8;
        // slots 2..5: Q-proj per scale -> QtT[z][d][208] (transposed, coalesced runs)
        for (int i = 0; i < 4; ++i) {
            const int sl = 2 + i, ch = chs[i];
            p.A[sl] = Eh + offE[i]; p.B[sl] = Wqh + offQ[i]; p.C[sl] = QtT + offQt[i];
            p.Mlim[sl] = 196; p.Nlim[sl] = ch; p.Klim[sl] = ch; p.nKt[sl] = ch / 32;
            p.lda[sl] = ch; p.ldb[sl] = ch; p.ldc[sl] = 208;
            p.divA[sl] = 4; p.sAhi[sl] = 196LL * ch; p.sAlo[sl] = 0;
            p.divB[sl] = 4; p.sBhi[sl] = 0; p.sBlo[sl] = (long long)ch * ch;
            p.divC[sl] = 1; p.sChi[sl] = 208LL * ch; p.sClo[sl] = 0;
            p.outMode[sl] = 2; p.alpha[sl] = 1.0f;
            p.mT[sl] = 2; p.nT[sl] = (ch + 127) / 128;
        }
        int cum = 0;
        const int blocks[6] = {800, 800, 128, 128, 256, 512};
        for (int sl = 0; sl < 6; ++sl) { cum += blocks[sl]; if (sl < 5) p.cumEnd[sl] = cum; }
        p.totW = cum;                       // 2624, divisible by 8
        gemm_w<<<2624, 256, 0, stream>>>(p);
    }

    // ---- Scores (raw) + stats, strip-resident ----
    {
        ScP p{};
        for (int s = 0; s < 4; ++s) {
            p.Qt[s] = QtT + offQt[s];
            p.C[s] = Sch + offSc[s];
            p.Part[s] = Part + (long long)s * 64 * 240;
            p.Mlim[s] = chs[s];
            p.sA[s] = 208LL * chs[s];
            p.sC[s] = 960LL * chs[s];
        }
        p.KT = KT;
        p.alpha = inv_sqrt_kv;
        gemm_s<<<512, 256, 0, stream>>>(p);
    }

    // ---- ctx: fused exp/softmax + PV (pipelined) ----
    {
        CtxP p{};
        p.V = Vh;
        const int nP[4] = {1, 1, 2, 4};
        for (int s = 0; s < 4; ++s) {
            p.S[s] = Sch + offSc[s];
            p.C[s] = Ctx + offCtx[s];
            p.Part[s] = Part + (long long)s * 64 * 240;
            p.ch[s] = chs[s];
            p.nPart[s] = nP[s];
            p.pinv[s] = 1.0f / (chs[s] * 960);
        }
        ctx_k<<<1024, 256, 0, stream>>>(p);
    }

    // ---- out-proj, all scales: out fp32 = Ctx (196 x 4ch) x Wo4^T (64x64) ----
    {
        BP p{};
        int cum = 0;
        for (int s = 0; s < 4; ++s) {
            const int ch = chs[s];
            p.A[s] = Ctx + offCtx[s]; p.B[s] = Wo4 + offQ[s]; p.C[s] = out + ooff[s];
            p.Mlim[s] = 196; p.Nlim[s] = ch; p.Klim[s] = 4 * ch; p.nKt[s] = ch / 8;
            p.lda[s] = 4 * ch; p.ldb[s] = 4 * ch; p.ldc[s] = ch;
            p.divA[s] = 1; p.sAhi[s] = 784LL * ch; p.sAlo[s] = 0;
            p.divB[s] = 1; p.sBhi[s] = 0; p.sBlo[s] = 0;
            p.divC[s] = 1; p.sChi[s] = 196LL * ch; p.sClo[s] = 0;
            p.outMode[s] = 0; p.alpha[s] = 1.0f;
            p.mT[s] = 4; p.nT[s] = ch / 64;
            cum += 4 * (ch / 64) * 16;
            if (s < 3) p.cumEnd[s] = cum;
        }
        p.cumEnd[3] = p.cumEnd[4] = cum;
        p.totW = cum;
        gemm_b<<<960, 128, 0, stream>>>(p);
    }
}

// Round 8
// 413.441 us; speedup vs baseline: 1.1472x; 1.1203x over previous
//
#include <hip/hip_runtime.h>

typedef _Float16 half_t;
typedef _Float16 h8 __attribute__((ext_vector_type(8)));
typedef _Float16 h4 __attribute__((ext_vector_type(4)));
typedef float f4v __attribute__((ext_vector_type(4)));

// async global->LDS, 16B per lane; lds base must be wave-uniform (HW: base + lane*16)
__device__ __forceinline__ void async16(half_t* l, const half_t* g)
{
    __builtin_amdgcn_global_load_lds(
        (const __attribute__((address_space(1))) void*)g,
        (__attribute__((address_space(3))) void*)l,
        16, 0, 0);
}

// ---------------- prep: cast fp32->fp16 (mode 0) or cast+replicate-4 (mode 1) ----------------
struct PrepArgs {
    const float* src[15];
    half_t* dst[15];
    int n[15];
    int mode[15];
    int lg2[15];
};

__global__ __launch_bounds__(256) void prep_k(PrepArgs a)
{
    const int seg = blockIdx.y;
    const int i8 = (blockIdx.x * 256 + threadIdx.x) * 8;
    if (i8 >= a.n[seg]) return;
    const float* s = a.src[seg] + i8;
    f4v v0 = *(const f4v*)s;
    f4v v1 = *(const f4v*)(s + 4);
    h8 o;
    o[0] = (half_t)v0[0]; o[1] = (half_t)v0[1]; o[2] = (half_t)v0[2]; o[3] = (half_t)v0[3];
    o[4] = (half_t)v1[0]; o[5] = (half_t)v1[1]; o[6] = (half_t)v1[2]; o[7] = (half_t)v1[3];
    if (a.mode[seg] == 0) {
        *(h8*)(a.dst[seg] + i8) = o;
    } else {
        const int lg = a.lg2[seg], ch = 1 << lg;
        const int e = i8 >> lg, d = i8 & (ch - 1);
        half_t* base = a.dst[seg] + ((long long)e << (lg + 2)) + d;
        #pragma unroll
        for (int r = 0; r < 4; ++r) *(h8*)(base + r * ch) = o;
    }
}

// ---------------- staged tile load with row/k-limit masking ----------------
__device__ __forceinline__ h8 ldtile(const half_t* __restrict__ base, int row, int kb,
                                     int ld, int rowLim, int Klim)
{
    h8 v = {0, 0, 0, 0, 0, 0, 0, 0};
    if (row >= rowLim) return v;
    const half_t* p = base + (long long)row * ld + kb;
    if (kb + 8 <= Klim) return *(const h8*)p;
    #pragma unroll
    for (int e = 0; e < 8; ++e) if (kb + e < Klim) v[e] = p[e];
    return v;
}

// ---------------- batch descriptor, up to 6 heterogeneous jobs ----------------
struct BP {
    const half_t* A[6]; const half_t* B[6]; void* C[6];
    int Mlim[6], Nlim[6], Klim[6], nKt[6], lda[6], ldb[6], ldc[6];
    int divA[6]; long long sAhi[6], sAlo[6];
    int divB[6]; long long sBhi[6], sBlo[6];
    int divC[6]; long long sChi[6], sClo[6];
    int outMode[6];          // 1 = fp16 normal, 2 = fp16 transposed (coalesced runs)
    float alpha[6];
    int mT[6], nT[6];
    int cumEnd[5];
    int totW;
};

// ---------------- 64x64 MFMA GEMM (2 waves), fp32 normal out — out-proj ----------------
__global__ __launch_bounds__(128)
void gemm_b(BP P)
{
    __shared__ __align__(16) half_t SM[64 * 72];
    half_t (*As)[32] = (half_t(*)[32])SM;
    half_t (*Bs)[32] = (half_t(*)[32])(SM + 2048);

    int b = blockIdx.x;
    int s = 0, basev = 0;
    #pragma unroll
    for (int i = 0; i < 5; ++i) if (b >= P.cumEnd[i]) { s = i + 1; basev = P.cumEnd[i]; }
    b -= basev;
    const int mTl = P.mT[s], nTl = P.nT[s];
    const int mt = b % mTl;
    const int t2 = b / mTl;
    const int nt = t2 % nTl;
    const int z  = t2 / nTl;

    const half_t* A  = P.A[s] + (long long)(z / P.divA[s]) * P.sAhi[s] + (long long)(z % P.divA[s]) * P.sAlo[s];
    const half_t* Bp = P.B[s] + (long long)(z / P.divB[s]) * P.sBhi[s] + (long long)(z % P.divB[s]) * P.sBlo[s];
    const int Mlim = P.Mlim[s], Klim = P.Klim[s], nKt = P.nKt[s];
    const int lda = P.lda[s], ldb = P.ldb[s], ldc = P.ldc[s];
    const float alpha = P.alpha[s];
    const int m0 = mt * 64, n0 = nt * 64;
    const int tid = threadIdx.x;
    const int lane = tid & 63, w = tid >> 6;
    const int l15 = lane & 15, q = lane >> 4;

    const int r0 = tid >> 2, kg = tid & 3;
    const int r1 = r0 + 32;

    f4v acc[4][2];
    #pragma unroll
    for (int i = 0; i < 4; ++i)
        #pragma unroll
        for (int j = 0; j < 2; ++j) acc[i][j] = (f4v){0.f, 0.f, 0.f, 0.f};

    for (int kt = 0; kt < nKt; ++kt) {
        const int kb = kt * 32 + kg * 8;
        h8 a0 = ldtile(A, m0 + r0, kb, lda, Mlim, Klim);
        h8 a1 = ldtile(A, m0 + r1, kb, lda, Mlim, Klim);
        h8 b0 = ldtile(Bp, n0 + r0, kb, ldb, 1 << 30, Klim);
        h8 b1 = ldtile(Bp, n0 + r1, kb, ldb, 1 << 30, Klim);
        __syncthreads();
        *(h8*)&As[r0][kg * 8] = a0;
        *(h8*)&As[r1][kg * 8] = a1;
        *(h8*)&Bs[r0][kg * 8] = b0;
        *(h8*)&Bs[r1][kg * 8] = b1;
        __syncthreads();
        h8 af[4], bf[2];
        #pragma unroll
        for (int mti = 0; mti < 4; ++mti) af[mti] = *(h8*)&As[mti * 16 + l15][q * 8];
        #pragma unroll
        for (int nti = 0; nti < 2; ++nti) bf[nti] = *(h8*)&Bs[w * 32 + nti * 16 + l15][q * 8];
        #pragma unroll
        for (int mti = 0; mti < 4; ++mti)
            #pragma unroll
            for (int nti = 0; nti < 2; ++nti)
                acc[mti][nti] = __builtin_amdgcn_mfma_f32_16x16x32_f16(af[mti], bf[nti], acc[mti][nti], 0, 0, 0);
    }

    float* Cz = (float*)P.C[s] + (long long)(z / P.divC[s]) * P.sChi[s] + (long long)(z % P.divC[s]) * P.sClo[s];
    #pragma unroll
    for (int mti = 0; mti < 4; ++mti)
        #pragma unroll
        for (int r = 0; r < 4; ++r) {
            const int row = m0 + mti * 16 + q * 4 + r;
            if (row < Mlim) {
                #pragma unroll
                for (int nti = 0; nti < 2; ++nti) {
                    const int col = n0 + w * 32 + nti * 16 + l15;
                    Cz[(long long)row * ldc + col] = acc[mti][nti][r] * alpha;
                }
            }
        }
}

// ---------------- 128x128 MFMA GEMM (256 threads) — K/V/Q projections in ONE launch ----------------
// Permuted-source staging (rule #21): stage lane l loads (row=l>>2, chunk=(l&3)^((l>>4)&3))
// -> global per-quarter-wave = 4 rows x 64B contiguous (round-4 coalescing), and the linear
// LDS write yields a layout whose fragment read (granule l15*4 + (q^((l15>>2)&3))) is a full
// permutation of each 1KB block: exactly 8 dword-accesses/bank, zero conflicts.
__global__ __launch_bounds__(256, 3)
void gemm_w(BP P)
{
    __shared__ __align__(16) half_t SMEM[16384];    // 2 x 8192 halves dbuf; T2 overlay 128x128

    const int per = gridDim.x >> 3;
    int wk = (blockIdx.x & 7) * per + (blockIdx.x >> 3);
    if (wk >= P.totW) return;
    int s = 0, basev = 0;
    #pragma unroll
    for (int i = 0; i < 5; ++i) if (wk >= P.cumEnd[i]) { s = i + 1; basev = P.cumEnd[i]; }
    wk -= basev;
    const int mTl = P.mT[s], nTl = P.nT[s];
    const int mt = wk % mTl;
    const int t2 = wk / mTl;
    const int nt = t2 % nTl;
    const int z  = t2 / nTl;

    const half_t* A  = P.A[s] + (long long)(z / P.divA[s]) * P.sAhi[s] + (long long)(z % P.divA[s]) * P.sAlo[s];
    const half_t* Bp = P.B[s] + (long long)(z / P.divB[s]) * P.sBhi[s] + (long long)(z % P.divB[s]) * P.sBlo[s];
    const int Mlim = P.Mlim[s], Nlim = P.Nlim[s], nKt = P.nKt[s];
    const int lda = P.lda[s], ldb = P.ldb[s], ldc = P.ldc[s];
    const float alpha = P.alpha[s];
    const int m0 = mt * 128, n0 = nt * 128;
    const int tid = threadIdx.x;
    const int lane = tid & 63, wv = tid >> 6;
    const int wm = wv & 1, wn = wv >> 1;
    const int l15 = lane & 15, q = lane >> 4;

    // stage lane mapping: row = lane>>2 (4 rows/quarter-wave, 64B contiguous each),
    // data chunk = (lane&3) ^ ((lane>>4)&3) (XOR within the 64B run; same address set)
    const int rl = lane >> 2;
    const int cD = (lane & 3) ^ ((lane >> 4) & 3);
    const int rA0 = min(m0 + wv * 16 + rl,       Mlim - 1);
    const int rA1 = min(m0 + 64 + wv * 16 + rl,  Mlim - 1);
    const int rB0 = min(n0 + wv * 16 + rl,       Nlim - 1);
    const int rB1 = min(n0 + 64 + wv * 16 + rl,  Nlim - 1);
    const half_t* gA0 = A  + (long long)rA0 * lda + cD * 8;
    const half_t* gA1 = A  + (long long)rA1 * lda + cD * 8;
    const half_t* gB0 = Bp + (long long)rB0 * ldb + cD * 8;
    const half_t* gB1 = Bp + (long long)rB1 * ldb + cD * 8;

    f4v acc[4][4];
    #pragma unroll
    for (int i = 0; i < 4; ++i)
        #pragma unroll
        for (int j = 0; j < 4; ++j) acc[i][j] = (f4v){0.f, 0.f, 0.f, 0.f};

    // wave wv writes g-blocks wv (rows +wv*16) and 4+wv (rows +64+wv*16); 512h (1KB) each
    auto stage = [&](int off) {
        half_t* base = SMEM + off;
        async16(base + wv * 512,              gA0);
        async16(base + (4 + wv) * 512,        gA1);
        async16(base + 4096 + wv * 512,       gB0);
        async16(base + 4096 + (4 + wv) * 512, gB1);
        gA0 += 32; gA1 += 32; gB0 += 32; gB1 += 32;
    };
    // fragment read: granule = l15*4 + (q ^ ((l15>>2)&3)) within g-block (wm*4+mi / wn*4+ni)
    // -> full 64-granule permutation per wave instruction: conflict-free
    auto compute = [&](int off) {
        const half_t* Asb = SMEM + off;
        const half_t* Bsb = Asb + 4096;
        const int sw = (q ^ ((l15 >> 2) & 3)) * 8 + l15 * 32;
        h8 af[4], bf[4];
        #pragma unroll
        for (int mi = 0; mi < 4; ++mi) af[mi] = *(const h8*)(Asb + (wm * 4 + mi) * 512 + sw);
        #pragma unroll
        for (int ni = 0; ni < 4; ++ni) bf[ni] = *(const h8*)(Bsb + (wn * 4 + ni) * 512 + sw);
        #pragma unroll
        for (int mi = 0; mi < 4; ++mi)
            #pragma unroll
            for (int ni = 0; ni < 4; ++ni)
                acc[mi][ni] = __builtin_amdgcn_mfma_f32_16x16x32_f16(af[mi], bf[ni], acc[mi][ni], 0, 0, 0);
    };

    stage(0);
    __syncthreads();
    for (int kt = 0; kt < nKt; kt += 2) {
        stage(8192);
        compute(0);
        __syncthreads();
        if (kt + 2 < nKt) stage(0);
        compute(8192);
        __syncthreads();
    }

    if (P.outMode[s] == 1) {
        half_t* Cz = (half_t*)P.C[s] + (long long)(z / P.divC[s]) * P.sChi[s] + (long long)(z % P.divC[s]) * P.sClo[s];
        #pragma unroll
        for (int mi = 0; mi < 4; ++mi)
            #pragma unroll
            for (int r = 0; r < 4; ++r) {
                const int row = m0 + wm * 64 + mi * 16 + q * 4 + r;
                if (row < Mlim) {
                    #pragma unroll
                    for (int ni = 0; ni < 4; ++ni) {
                        const int col = n0 + wn * 64 + ni * 16 + l15;
                        if (col < Nlim) Cz[(long long)row * ldc + col] = (half_t)(acc[mi][ni][r] * alpha);
                    }
                }
            }
    } else {
        // coalesced transpose epilogue: C[col][m], ldc-padded rows; pad-writes are garbage
        // that downstream consumers never read meaningfully (zero-masked A-columns).
        // Single pass through overlay T2[128 cols][128 m], h4-granule XOR swizzle.
        half_t (*T2)[128] = (half_t(*)[128])SMEM;
        half_t* Cz = (half_t*)P.C[s] + (long long)(z / P.divC[s]) * P.sChi[s] + (long long)(z % P.divC[s]) * P.sClo[s];
        #pragma unroll
        for (int mi = 0; mi < 4; ++mi)
            #pragma unroll
            for (int ni = 0; ni < 4; ++ni) {
                h4 pk;
                #pragma unroll
                for (int r = 0; r < 4; ++r) pk[r] = (half_t)(acc[mi][ni][r] * alpha);
                const int col = wn * 64 + ni * 16 + l15;
                const int g   = wm * 16 + mi * 4 + q;               // m-group (4 halves)
                *(h4*)&T2[col][4 * (g ^ (col & 31))] = pk;
            }
        __syncthreads();
        {
            const int col  = tid >> 1;
            const int coff = (tid & 1) * 64;
            const int gb   = (tid & 1) * 16;
            const int mbase = m0 + coff;
            const int nfull = max(0, min(64, ldc - mbase)) >> 3;    // whole h8 runs in-row
            if (n0 + col < Nlim && nfull > 0) {
                half_t* rp = Cz + (long long)(n0 + col) * ldc + mbase;
                for (int j = 0; j < nfull; ++j) {
                    h4 lo = *(h4*)&T2[col][4 * ((gb + 2 * j)     ^ (col & 31))];
                    h4 hi = *(h4*)&T2[col][4 * ((gb + 2 * j + 1) ^ (col & 31))];
                    h8 v = {lo[0], lo[1], lo[2], lo[3], hi[0], hi[1], hi[2], hi[3]};
                    *(h8*)(rp + j * 8) = v;
                }
            }
        }
    }
}

// ---------------- scores: A-strip-resident GEMM + fused IN-stat partials ----------------
// B = KT[h][960][3200] (global-n rows, pad cols garbage — masked by zero A-columns).
// z enumerated h-major so co-XCD blocks share a head: their KT windows are adjacent
// column ranges of the SAME rows -> full line utilization, ~3 MB/XCD L2 footprint.
struct ScP {
    const half_t* Qt[4];
    const half_t* KT;
    half_t* C[4];
    float* Part[4];
    int Mlim[4];
    long long sA[4], sC[4];
    float alpha;
};

__global__ __launch_bounds__(256)
void gemm_s(ScP P)
{
    __shared__ __align__(16) half_t As[128][232];   // full-K strip (196 -> zero-pad)
    __shared__ __align__(16) half_t Bs[128][72];    // 64-wide B chunk
    __shared__ float red[8];

    const int per = gridDim.x >> 3;                 // 512/8 = 64 -> 8 z per XCD
    int wk = (blockIdx.x & 7) * per + (blockIdx.x >> 3);
    const int zl = wk >> 3, r = wk & 7;
    int s, mt;
    if (r < 1)      { s = 0; mt = 0; }
    else if (r < 2) { s = 1; mt = 0; }
    else if (r < 4) { s = 2; mt = r - 2; }
    else            { s = 3; mt = r - 4; }
    const int h = zl >> 4, b = zl & 15;             // h-major enumeration
    const int zq = b * 4 + h;                       // storage order of Qt/C/Part planes

    const half_t* A = P.Qt[s] + (long long)zq * P.sA[s] + (long long)mt * 128 * 208;
    const half_t* B = P.KT + (long long)h * 3072000 + (long long)b * 196;   // [960][3200] window
    const int rowLim = P.Mlim[s] - mt * 128;
    const float alpha = P.alpha;

    const int tid = threadIdx.x;
    const int lane = tid & 63, wv = tid >> 6;
    const int wm = wv & 1, wn = wv >> 1;
    const int l15 = lane & 15, q = lane >> 4;
    const int r0 = tid >> 2, kg = tid & 3;

    #pragma unroll
    for (int c = 0; c < 7; ++c) {
        const int kb = c * 32 + kg * 8;
        h8 a0 = ldtile(A, r0, kb, 208, rowLim, 196);
        h8 a1 = ldtile(A, r0 + 64, kb, 208, rowLim, 196);
        *(h8*)&As[r0][kb] = a0;
        *(h8*)&As[r0 + 64][kb] = a1;
    }

    half_t* Cz = P.C[s] + (long long)zq * P.sC[s] + (long long)mt * 128 * 960;
    float sv = 0.f, qq = 0.f;

    for (int nt = 0; nt < 8; ++nt) {
        f4v acc[4][4];
        #pragma unroll
        for (int i = 0; i < 4; ++i)
            #pragma unroll
            for (int j = 0; j < 4; ++j) acc[i][j] = (f4v){0.f, 0.f, 0.f, 0.f};

        const int j0 = nt * 128;
        #pragma unroll
        for (int c2 = 0; c2 < 4; ++c2) {
            h8 b00 = ldtile(B, j0 + r0,      c2 * 64 + kg * 8,      3200, 960, 196);
            h8 b01 = ldtile(B, j0 + r0,      c2 * 64 + 32 + kg * 8, 3200, 960, 196);
            h8 b10 = ldtile(B, j0 + r0 + 64, c2 * 64 + kg * 8,      3200, 960, 196);
            h8 b11 = ldtile(B, j0 + r0 + 64, c2 * 64 + 32 + kg * 8, 3200, 960, 196);
            __syncthreads();
            *(h8*)&Bs[r0][kg * 8] = b00;
            *(h8*)&Bs[r0][32 + kg * 8] = b01;
            *(h8*)&Bs[r0 + 64][kg * 8] = b10;
            *(h8*)&Bs[r0 + 64][32 + kg * 8] = b11;
            __syncthreads();
            const int nkk = (c2 < 3) ? 2 : 1;
            for (int kk = 0; kk < nkk; ++kk) {
                const int base = c2 * 64 + kk * 32;
                h8 af[4], bf[4];
                #pragma unroll
                for (int mi = 0; mi < 4; ++mi) af[mi] = *(h8*)&As[wm * 64 + mi * 16 + l15][base + q * 8];
                #pragma unroll
                for (int ni = 0; ni < 4; ++ni) bf[ni] = *(h8*)&Bs[wn * 64 + ni * 16 + l15][kk * 32 + q * 8];
                #pragma unroll
                for (int mi = 0; mi < 4; ++mi)
                    #pragma unroll
                    for (int ni = 0; ni < 4; ++ni)
                        acc[mi][ni] = __builtin_amdgcn_mfma_f32_16x16x32_f16(af[mi], bf[ni], acc[mi][ni], 0, 0, 0);
            }
        }
        #pragma unroll
        for (int mi = 0; mi < 4; ++mi)
            #pragma unroll
            for (int rr = 0; rr < 4; ++rr) {
                const int rowl = wm * 64 + mi * 16 + q * 4 + rr;
                #pragma unroll
                for (int ni = 0; ni < 4; ++ni) {
                    const int col = j0 + wn * 64 + ni * 16 + l15;
                    const float v = acc[mi][ni][rr] * alpha;
                    sv += v; qq += v * v;
                    if (rowl < rowLim && col < 960)
                        Cz[(long long)rowl * 960 + col] = (half_t)v;
                }
            }
    }

    #pragma unroll
    for (int o = 32; o > 0; o >>= 1) {
        sv += __shfl_down(sv, o, 64);
        qq += __shfl_down(qq, o, 64);
    }
    if (lane == 0) { red[wv] = sv; red[4 + wv] = qq; }
    __syncthreads();
    if (tid == 0) {
        float* PO = P.Part[s] + (long long)zq * 240 + mt * 2;
        PO[0] = red[0] + red[1] + red[2] + red[3];
        PO[1] = red[4] + red[5] + red[6] + red[7];
    }
}

// ---------------- ctx: fused IN-scale + exp + PV GEMM + denominator normalize ----------------
struct CtxP {
    const half_t* V;
    const half_t* S[4];
    half_t* C[4];
    const float* Part[4];
    int ch[4];
    int nPart[4];
    float pinv[4];
};

__global__ __launch_bounds__(256)
void ctx_k(CtxP P)
{
    __shared__ __align__(16) half_t As[128][40];
    __shared__ __align__(16) half_t Bs[128][40];
    __shared__ float denomP[128][4];
    __shared__ float denom[128];

    const int per = gridDim.x >> 3;                 // 1024/8 = 128 -> 8 z per XCD
    int wk = (blockIdx.x & 7) * per + (blockIdx.x >> 3);
    const int z = wk >> 4;
    const int r = wk & 15;
    int s, mt, nt;
    if (r < 2)      { s = 0; mt = r;            nt = 0; }
    else if (r < 4) { s = 1; mt = r - 2;        nt = 0; }
    else if (r < 8) { s = 2; mt = (r - 4) >> 1; nt = (r - 4) & 1; }
    else            { s = 3; mt = (r - 8) >> 2; nt = (r - 8) & 3; }
    const int b = z >> 2, h = z & 3;
    const int chS = P.ch[s];

    const float* part = P.Part[s] + (long long)z * 240;
    float Ssum = 0.f, Qsum = 0.f;
    for (int i = 0; i < P.nPart[s]; ++i) { Ssum += part[i * 2]; Qsum += part[i * 2 + 1]; }
    const float mn = Ssum * P.pinv[s];
    const float rs = rsqrtf(fmaxf(Qsum * P.pinv[s] - mn * mn, 0.f) + 1e-5f);

    const half_t* Av  = P.V + (long long)h * 3010560 + (long long)b * 188160;   // [196][960]
    const half_t* Bsc = P.S[s] + (long long)z * 960 * chS;                      // [ch][960] raw
    const int m0 = mt * 128, n0 = nt * 128;

    const int tid = threadIdx.x;
    const int lane = tid & 63, wv = tid >> 6;
    const int wm = wv & 1, wn = wv >> 1;
    const int l15 = lane & 15, q = lane >> 4;
    const int r0 = tid >> 2, kg = tid & 3;
    const int d0 = n0 + r0, d1 = n0 + r0 + 64;
    const bool ok0 = d0 < chS, ok1 = d1 < chS;

    f4v acc[4][4];
    #pragma unroll
    for (int i = 0; i < 4; ++i)
        #pragma unroll
        for (int j = 0; j < 4; ++j) acc[i][j] = (f4v){0.f, 0.f, 0.f, 0.f};

    float ds0 = 0.f, ds1 = 0.f;

    // prologue: loads for kt=0
    h8 a0n = ldtile(Av, m0 + r0, kg * 8, 960, 196, 960);
    h8 a1n = ldtile(Av, m0 + r0 + 64, kg * 8, 960, 196, 960);
    h8 s0n = {0,0,0,0,0,0,0,0}, s1n = {0,0,0,0,0,0,0,0};
    if (ok0) s0n = *(const h8*)(Bsc + (long long)d0 * 960 + kg * 8);
    if (ok1) s1n = *(const h8*)(Bsc + (long long)d1 * 960 + kg * 8);

    for (int kt = 0; kt < 30; ++kt) {
        h8 e0 = {0,0,0,0,0,0,0,0}, e1 = {0,0,0,0,0,0,0,0};
        if (ok0) {
            #pragma unroll
            for (int e = 0; e < 8; ++e) { float ev = __expf((float)s0n[e] * rs); ds0 += ev; e0[e] = (half_t)ev; }
        }
        if (ok1) {
            #pragma unroll
            for (int e = 0; e < 8; ++e) { float ev = __expf((float)s1n[e] * rs); ds1 += ev; e1[e] = (half_t)ev; }
        }
        h8 a0c = a0n, a1c = a1n;
        __syncthreads();
        *(h8*)&As[r0][kg * 8] = a0c;
        *(h8*)&As[r0 + 64][kg * 8] = a1c;
        *(h8*)&Bs[r0][kg * 8] = e0;
        *(h8*)&Bs[r0 + 64][kg * 8] = e1;
        __syncthreads();
        if (kt < 29) {
            const int kb = (kt + 1) * 32 + kg * 8;
            a0n = ldtile(Av, m0 + r0, kb, 960, 196, 960);
            a1n = ldtile(Av, m0 + r0 + 64, kb, 960, 196, 960);
            if (ok0) s0n = *(const h8*)(Bsc + (long long)d0 * 960 + kb);
            if (ok1) s1n = *(const h8*)(Bsc + (long long)d1 * 960 + kb);
        }
        h8 af[4], bf[4];
        #pragma unroll
        for (int mi = 0; mi < 4; ++mi) af[mi] = *(h8*)&As[wm * 64 + mi * 16 + l15][q * 8];
        #pragma unroll
        for (int ni = 0; ni < 4; ++ni) bf[ni] = *(h8*)&Bs[wn * 64 + ni * 16 + l15][q * 8];
        #pragma unroll
        for (int mi = 0; mi < 4; ++mi)
            #pragma unroll
            for (int ni = 0; ni < 4; ++ni)
                acc[mi][ni] = __builtin_amdgcn_mfma_f32_16x16x32_f16(af[mi], bf[ni], acc[mi][ni], 0, 0, 0);
    }

    denomP[r0][kg] = ds0;
    denomP[r0 + 64][kg] = ds1;
    __syncthreads();
    if (tid < 128) denom[tid] = denomP[tid][0] + denomP[tid][1] + denomP[tid][2] + denomP[tid][3];
    __syncthreads();

    half_t* Cz = P.C[s] + (long long)b * 784 * chS + (long long)h * chS;
    const int ldc = 4 * chS;
    #pragma unroll
    for (int ni = 0; ni < 4; ++ni) {
        const int coll = wn * 64 + ni * 16 + l15;
        const int col = n0 + coll;
        if (col < chS) {
            const float sc = 0.25f / denom[coll];
            #pragma unroll
            for (int mi = 0; mi < 4; ++mi)
                #pragma unroll
                for (int rr = 0; rr < 4; ++rr) {
                    const int row = m0 + wm * 64 + mi * 16 + q * 4 + rr;
                    if (row < 196)
                        Cz[(long long)row * ldc + col] = (half_t)(acc[mi][ni][rr] * sc);
                }
        }
    }
}

// ---------------- launcher ----------------
extern "C" void kernel_launch(void* const* d_in, const int* in_sizes, int n_in,
                              void* d_out, int out_size, void* d_ws, size_t ws_size,
                              hipStream_t stream)
{
    const float* emb[4]  = {(const float*)d_in[0], (const float*)d_in[1],
                            (const float*)d_in[2], (const float*)d_in[3]};
    const float* emb_all = (const float*)d_in[4];
    const float* Wq[4]   = {(const float*)d_in[5], (const float*)d_in[7],
                            (const float*)d_in[9], (const float*)d_in[11]};
    const float* Wo[4]   = {(const float*)d_in[6], (const float*)d_in[8],
                            (const float*)d_in[10], (const float*)d_in[12]};
    const float* Wk = (const float*)d_in[13];
    const float* Wv = (const float*)d_in[14];
    float* out = (float*)d_out;

    half_t* hb = (half_t*)d_ws;
    half_t* EAh = hb;                              // 3010560
    half_t* Eh  = EAh + 3010560;                   // 3010560
    half_t* Wkh = Eh  + 3010560;                   // 3686400
    half_t* Wvh = Wkh + 3686400;                   // 3686400
    half_t* Wqh = Wvh + 3686400;                   // 1392640
    half_t* Wo4 = Wqh + 1392640;                   // 1392640
    half_t* KT  = Wo4 + 1392640;                   // [h][960][3200]        = 12288000 (slot 12779520)
    half_t* Vh  = KT  + 12779520;                  // [h][3136][960]        = 12042240
    half_t* QtT = Vh  + 12042240;                  // per-scale [64][ch][208] = 12779520
    half_t* Ctx = QtT + 12779520;                  // per-scale [16][196][4ch] = 12042240
    half_t* Sch = Ctx + 12042240;                  // per-scale [64][ch][960] raw = 58982400
    float*  Part = (float*)(Sch + 58982400);       // 4 * 64 * 240 floats

    const int  chs[4]   = {64, 128, 256, 512};
    const int  lg2c[4]  = {6, 7, 8, 9};
    const long long offE[4]   = {0, 200704, 602112, 1404928};
    const long long offQ[4]   = {0, 16384, 81920, 344064};
    const long long offQt[4]  = {0, 851968, 2555904, 5963776};
    const long long offSc[4]  = {0, 3932160, 11796480, 27525120};
    const long long offCtx[4] = {0, 802816, 2408448, 5619712};
    const long long ooff[4]   = {0, 200704, 602112, 1404928};
    const float inv_sqrt_kv = 0.03227486121839514f;

    // ---- prep ----
    PrepArgs pa;
    pa.src[0] = emb_all; pa.dst[0] = EAh; pa.n[0] = 3010560; pa.mode[0] = 0; pa.lg2[0] = 0;
    for (int i = 0; i < 4; ++i) {
        pa.src[1 + i] = emb[i]; pa.dst[1 + i] = Eh + offE[i];
        pa.n[1 + i] = (int)(3136LL * chs[i]); pa.mode[1 + i] = 0; pa.lg2[1 + i] = 0;
    }
    pa.src[5] = Wk; pa.dst[5] = Wkh; pa.n[5] = 3686400; pa.mode[5] = 0; pa.lg2[5] = 0;
    pa.src[6] = Wv; pa.dst[6] = Wvh; pa.n[6] = 3686400; pa.mode[6] = 0; pa.lg2[6] = 0;
    for (int i = 0; i < 4; ++i) {
        pa.src[7 + i] = Wq[i]; pa.dst[7 + i] = Wqh + offQ[i];
        pa.n[7 + i] = 4 * chs[i] * chs[i]; pa.mode[7 + i] = 0; pa.lg2[7 + i] = 0;
        pa.src[11 + i] = Wo[i]; pa.dst[11 + i] = Wo4 + offQ[i];
        pa.n[11 + i] = chs[i] * chs[i]; pa.mode[11 + i] = 1; pa.lg2[11 + i] = lg2c[i];
    }
    prep_k<<<dim3(1800, 15), 256, 0, stream>>>(pa);

    // ---- K-proj + V-proj + Q-proj (all scales) in ONE 128x128 launch ----
    {
        BP p{};
        // slot 0: K projection -> KT[h][col j][n 3200] (transposed, coalesced runs)
        p.A[0] = EAh; p.B[0] = Wkh; p.C[0] = KT;
        p.Mlim[0] = 3136; p.Nlim[0] = 960; p.Klim[0] = 960; p.nKt[0] = 30;
        p.lda[0] = 960; p.ldb[0] = 960; p.ldc[0] = 3200;
        p.divA[0] = 1; p.sAhi[0] = 0; p.sAlo[0] = 0;
        p.divB[0] = 1; p.sBhi[0] = 921600; p.sBlo[0] = 0;
        p.divC[0] = 1; p.sChi[0] = 3072000; p.sClo[0] = 0;
        p.outMode[0] = 2; p.alpha[0] = 1.0f;
        p.mT[0] = 25; p.nT[0] = 8;
        // slot 1: V projection -> Vh[h][3136][960] (normal)
        p.A[1] = EAh; p.B[1] = Wvh; p.C[1] = Vh;
        p.Mlim[1] = 3136; p.Nlim[1] = 960; p.Klim[1] = 960; p.nKt[1] = 30;
        p.lda[1] = 960; p.ldb[1] = 960; p.ldc[1] = 960;
        p.divA[1] = 1; p.sAhi[1] = 0; p.sAlo[1] = 0;
        p.divB[1] = 1; p.sBhi[1] = 921600; p.sBlo[1] = 0;
        p.divC[1] = 1; p.sChi[1] = 3010560; p.sClo[1] = 0;
        p.outMode[1] = 1; p.alpha[1] = 1.0f;
        p.mT[1] = 25; p.nT[1] = 8;
        // slots 2..5: Q-proj per scale -> QtT[z][d][208] (transposed, coalesced runs)
        for (int i = 0; i < 4; ++i) {
            const int sl = 2 + i, ch = chs[i];
            p.A[sl] = Eh + offE[i]; p.B[sl] = Wqh + offQ[i]; p.C[sl] = QtT + offQt[i];
            p.Mlim[sl] = 196; p.Nlim[sl] = ch; p.Klim[sl] = ch; p.nKt[sl] = ch / 32;
            p.lda[sl] = ch; p.ldb[sl] = ch; p.ldc[sl] = 208;
            p.divA[sl] = 4; p.sAhi[sl] = 196LL * ch; p.sAlo[sl] = 0;
            p.divB[sl] = 4; p.sBhi[sl] = 0; p.sBlo[sl] = (long long)ch * ch;
            p.divC[sl] = 1; p.sChi[sl] = 208LL * ch; p.sClo[sl] = 0;
            p.outMode[sl] = 2; p.alpha[sl] = 1.0f;
            p.mT[sl] = 2; p.nT[sl] = (ch + 127) / 128;
        }
        int cum = 0;
        const int blocks[6] = {800, 800, 128, 128, 256, 512};
        for (int sl = 0; sl < 6; ++sl) { cum += blocks[sl]; if (sl < 5) p.cumEnd[sl] = cum; }
        p.totW = cum;                       // 2624, divisible by 8
        gemm_w<<<2624, 256, 0, stream>>>(p);
    }

    // ---- Scores (raw) + stats, strip-resident ----
    {
        ScP p{};
        for (int s = 0; s < 4; ++s) {
            p.Qt[s] = QtT + offQt[s];
            p.C[s] = Sch + offSc[s];
            p.Part[s] = Part + (long long)s * 64 * 240;
            p.Mlim[s] = chs[s];
            p.sA[s] = 208LL * chs[s];
            p.sC[s] = 960LL * chs[s];
        }
        p.KT = KT;
        p.alpha = inv_sqrt_kv;
        gemm_s<<<512, 256, 0, stream>>>(p);
    }

    // ---- ctx: fused exp/softmax + PV (pipelined) ----
    {
        CtxP p{};
        p.V = Vh;
        const int nP[4] = {1, 1, 2, 4};
        for (int s = 0; s < 4; ++s) {
            p.S[s] = Sch + offSc[s];
            p.C[s] = Ctx + offCtx[s];
            p.Part[s] = Part + (long long)s * 64 * 240;
            p.ch[s] = chs[s];
            p.nPart[s] = nP[s];
            p.pinv[s] = 1.0f / (chs[s] * 960);
        }
        ctx_k<<<1024, 256, 0, stream>>>(p);
    }

    // ---- out-proj, all scales: out fp32 = Ctx (196 x 4ch) x Wo4^T (64x64) ----
    {
        BP p{};
        int cum = 0;
        for (int s = 0; s < 4; ++s) {
            const int ch = chs[s];
            p.A[s] = Ctx + offCtx[s]; p.B[s] = Wo4 + offQ[s]; p.C[s] = out + ooff[s];
            p.Mlim[s] = 196; p.Nlim[s] = ch; p.Klim[s] = 4 * ch; p.nKt[s] = ch / 8;
            p.lda[s] = 4 * ch; p.ldb[s] = 4 * ch; p.ldc[s] = ch;
            p.divA[s] = 1; p.sAhi[s] = 784LL * ch; p.sAlo[s] = 0;
            p.divB[s] = 1; p.sBhi[s] = 0; p.sBlo[s] = 0;
            p.divC[s] = 1; p.sChi[s] = 196LL * ch; p.sClo[s] = 0;
            p.outMode[s] = 0; p.alpha[s] = 1.0f;
            p.mT[s] = 4; p.nT[s] = ch / 64;
            cum += 4 * (ch / 64) * 16;
            if (s < 3) p.cumEnd[s] = cum;
        }
        p.cumEnd[3] = p.cumEnd[4] = cum;
        p.totW = cum;
        gemm_b<<<960, 128, 0, stream>>>(p);
    }
}

// Round 9
// 381.510 us; speedup vs baseline: 1.2432x; 1.0837x over previous
//
#include <hip/hip_runtime.h>

typedef _Float16 half_t;
typedef _Float16 h8 __attribute__((ext_vector_type(8)));
typedef _Float16 h4 __attribute__((ext_vector_type(4)));
typedef float f4v __attribute__((ext_vector_type(4)));

// async global->LDS, 16B per lane; lds base must be wave-uniform (HW: base + lane*16)
__device__ __forceinline__ void async16(half_t* l, const half_t* g)
{
    __builtin_amdgcn_global_load_lds(
        (const __attribute__((address_space(1))) void*)g,
        (__attribute__((address_space(3))) void*)l,
        16, 0, 0);
}

// ---------------- prep: cast fp32->fp16 (mode 0) or cast+replicate-4 (mode 1) ----------------
struct PrepArgs {
    const float* src[15];
    half_t* dst[15];
    int n[15];
    int mode[15];
    int lg2[15];
};

__global__ __launch_bounds__(256) void prep_k(PrepArgs a)
{
    const int seg = blockIdx.y;
    const int i8 = (blockIdx.x * 256 + threadIdx.x) * 8;
    if (i8 >= a.n[seg]) return;
    const float* s = a.src[seg] + i8;
    f4v v0 = *(const f4v*)s;
    f4v v1 = *(const f4v*)(s + 4);
    h8 o;
    o[0] = (half_t)v0[0]; o[1] = (half_t)v0[1]; o[2] = (half_t)v0[2]; o[3] = (half_t)v0[3];
    o[4] = (half_t)v1[0]; o[5] = (half_t)v1[1]; o[6] = (half_t)v1[2]; o[7] = (half_t)v1[3];
    if (a.mode[seg] == 0) {
        *(h8*)(a.dst[seg] + i8) = o;
    } else {
        const int lg = a.lg2[seg], ch = 1 << lg;
        const int e = i8 >> lg, d = i8 & (ch - 1);
        half_t* base = a.dst[seg] + ((long long)e << (lg + 2)) + d;
        #pragma unroll
        for (int r = 0; r < 4; ++r) *(h8*)(base + r * ch) = o;
    }
}

// ---------------- staged tile load with row/k-limit masking ----------------
__device__ __forceinline__ h8 ldtile(const half_t* __restrict__ base, int row, int kb,
                                     int ld, int rowLim, int Klim)
{
    h8 v = {0, 0, 0, 0, 0, 0, 0, 0};
    if (row >= rowLim) return v;
    const half_t* p = base + (long long)row * ld + kb;
    if (kb + 8 <= Klim) return *(const h8*)p;
    #pragma unroll
    for (int e = 0; e < 8; ++e) if (kb + e < Klim) v[e] = p[e];
    return v;
}

// ---------------- batch descriptor, up to 6 heterogeneous jobs ----------------
struct BP {
    const half_t* A[6]; const half_t* B[6]; void* C[6];
    int Mlim[6], Nlim[6], Klim[6], nKt[6], lda[6], ldb[6], ldc[6];
    int divA[6]; long long sAhi[6], sAlo[6];
    int divB[6]; long long sBhi[6], sBlo[6];
    int divC[6]; long long sChi[6], sClo[6];
    int outMode[6];          // 1 = fp16 normal, 2 = fp16 transposed (coalesced runs)
    float alpha[6];
    int mT[6], nT[6];
    int cumEnd[5];
    int totW;
};

// ---------------- 64x64 MFMA GEMM (2 waves), fp32 normal out — out-proj ----------------
__global__ __launch_bounds__(128)
void gemm_b(BP P)
{
    __shared__ __align__(16) half_t SM[64 * 72];
    half_t (*As)[32] = (half_t(*)[32])SM;
    half_t (*Bs)[32] = (half_t(*)[32])(SM + 2048);

    int b = blockIdx.x;
    int s = 0, basev = 0;
    #pragma unroll
    for (int i = 0; i < 5; ++i) if (b >= P.cumEnd[i]) { s = i + 1; basev = P.cumEnd[i]; }
    b -= basev;
    const int mTl = P.mT[s], nTl = P.nT[s];
    const int mt = b % mTl;
    const int t2 = b / mTl;
    const int nt = t2 % nTl;
    const int z  = t2 / nTl;

    const half_t* A  = P.A[s] + (long long)(z / P.divA[s]) * P.sAhi[s] + (long long)(z % P.divA[s]) * P.sAlo[s];
    const half_t* Bp = P.B[s] + (long long)(z / P.divB[s]) * P.sBhi[s] + (long long)(z % P.divB[s]) * P.sBlo[s];
    const int Mlim = P.Mlim[s], Klim = P.Klim[s], nKt = P.nKt[s];
    const int lda = P.lda[s], ldb = P.ldb[s], ldc = P.ldc[s];
    const float alpha = P.alpha[s];
    const int m0 = mt * 64, n0 = nt * 64;
    const int tid = threadIdx.x;
    const int lane = tid & 63, w = tid >> 6;
    const int l15 = lane & 15, q = lane >> 4;

    const int r0 = tid >> 2, kg = tid & 3;
    const int r1 = r0 + 32;

    f4v acc[4][2];
    #pragma unroll
    for (int i = 0; i < 4; ++i)
        #pragma unroll
        for (int j = 0; j < 2; ++j) acc[i][j] = (f4v){0.f, 0.f, 0.f, 0.f};

    for (int kt = 0; kt < nKt; ++kt) {
        const int kb = kt * 32 + kg * 8;
        h8 a0 = ldtile(A, m0 + r0, kb, lda, Mlim, Klim);
        h8 a1 = ldtile(A, m0 + r1, kb, lda, Mlim, Klim);
        h8 b0 = ldtile(Bp, n0 + r0, kb, ldb, 1 << 30, Klim);
        h8 b1 = ldtile(Bp, n0 + r1, kb, ldb, 1 << 30, Klim);
        __syncthreads();
        *(h8*)&As[r0][kg * 8] = a0;
        *(h8*)&As[r1][kg * 8] = a1;
        *(h8*)&Bs[r0][kg * 8] = b0;
        *(h8*)&Bs[r1][kg * 8] = b1;
        __syncthreads();
        h8 af[4], bf[2];
        #pragma unroll
        for (int mti = 0; mti < 4; ++mti) af[mti] = *(h8*)&As[mti * 16 + l15][q * 8];
        #pragma unroll
        for (int nti = 0; nti < 2; ++nti) bf[nti] = *(h8*)&Bs[w * 32 + nti * 16 + l15][q * 8];
        #pragma unroll
        for (int mti = 0; mti < 4; ++mti)
            #pragma unroll
            for (int nti = 0; nti < 2; ++nti)
                acc[mti][nti] = __builtin_amdgcn_mfma_f32_16x16x32_f16(af[mti], bf[nti], acc[mti][nti], 0, 0, 0);
    }

    float* Cz = (float*)P.C[s] + (long long)(z / P.divC[s]) * P.sChi[s] + (long long)(z % P.divC[s]) * P.sClo[s];
    #pragma unroll
    for (int mti = 0; mti < 4; ++mti)
        #pragma unroll
        for (int r = 0; r < 4; ++r) {
            const int row = m0 + mti * 16 + q * 4 + r;
            if (row < Mlim) {
                #pragma unroll
                for (int nti = 0; nti < 2; ++nti) {
                    const int col = n0 + w * 32 + nti * 16 + l15;
                    Cz[(long long)row * ldc + col] = acc[mti][nti][r] * alpha;
                }
            }
        }
}

// ---------------- 128x128 MFMA GEMM (256 threads) — K/V/Q projections in ONE launch ----------------
// STRATIFIED XCD mapping: each XCD gets the x-th contiguous 1/8 chunk of EVERY job segment
// (all segment lengths divisible by 8) -> per-XCD K-iteration totals exactly balanced (7376),
// vs 9840/1584 (6x imbalance) under the old contiguous-chunk swizzle. Locality unchanged:
// co-XCD blocks remain wk-contiguous within a segment.
// Staging: permuted-source (r8) — coalesced 4-rows-x-64B global reads, conflict pattern
// equivalent to r4 (measured: no cost).
__global__ __launch_bounds__(256, 3)
void gemm_w(BP P)
{
    __shared__ __align__(16) half_t SMEM[16384];    // 2 x 8192 halves dbuf; T2 overlay 128x128

    const int xcd = blockIdx.x & 7;
    const int rnk = blockIdx.x >> 3;
    int wk = P.totW;
    {
        int prev = 0, accs = 0;
        #pragma unroll
        for (int i = 0; i < 6; ++i) {
            const int end = (i < 5) ? P.cumEnd[i] : P.totW;
            const int share = (end - prev) >> 3;        // segment lengths divisible by 8
            if (rnk >= accs && rnk < accs + share) wk = prev + xcd * share + (rnk - accs);
            accs += share;
            prev = end;
        }
    }
    if (wk >= P.totW) return;
    int s = 0, basev = 0;
    #pragma unroll
    for (int i = 0; i < 5; ++i) if (wk >= P.cumEnd[i]) { s = i + 1; basev = P.cumEnd[i]; }
    wk -= basev;
    const int mTl = P.mT[s], nTl = P.nT[s];
    const int mt = wk % mTl;
    const int t2 = wk / mTl;
    const int nt = t2 % nTl;
    const int z  = t2 / nTl;

    const half_t* A  = P.A[s] + (long long)(z / P.divA[s]) * P.sAhi[s] + (long long)(z % P.divA[s]) * P.sAlo[s];
    const half_t* Bp = P.B[s] + (long long)(z / P.divB[s]) * P.sBhi[s] + (long long)(z % P.divB[s]) * P.sBlo[s];
    const int Mlim = P.Mlim[s], Nlim = P.Nlim[s], nKt = P.nKt[s];
    const int lda = P.lda[s], ldb = P.ldb[s], ldc = P.ldc[s];
    const float alpha = P.alpha[s];
    const int m0 = mt * 128, n0 = nt * 128;
    const int tid = threadIdx.x;
    const int lane = tid & 63, wv = tid >> 6;
    const int wm = wv & 1, wn = wv >> 1;
    const int l15 = lane & 15, q = lane >> 4;

    // stage lane mapping: row = lane>>2 (4 rows/quarter-wave, 64B contiguous each),
    // data chunk = (lane&3) ^ ((lane>>4)&3) (XOR within the 64B run; same address set)
    const int rl = lane >> 2;
    const int cD = (lane & 3) ^ ((lane >> 4) & 3);
    const int rA0 = min(m0 + wv * 16 + rl,       Mlim - 1);
    const int rA1 = min(m0 + 64 + wv * 16 + rl,  Mlim - 1);
    const int rB0 = min(n0 + wv * 16 + rl,       Nlim - 1);
    const int rB1 = min(n0 + 64 + wv * 16 + rl,  Nlim - 1);
    const half_t* gA0 = A  + (long long)rA0 * lda + cD * 8;
    const half_t* gA1 = A  + (long long)rA1 * lda + cD * 8;
    const half_t* gB0 = Bp + (long long)rB0 * ldb + cD * 8;
    const half_t* gB1 = Bp + (long long)rB1 * ldb + cD * 8;

    f4v acc[4][4];
    #pragma unroll
    for (int i = 0; i < 4; ++i)
        #pragma unroll
        for (int j = 0; j < 4; ++j) acc[i][j] = (f4v){0.f, 0.f, 0.f, 0.f};

    // wave wv writes g-blocks wv (rows +wv*16) and 4+wv (rows +64+wv*16); 512h (1KB) each
    auto stage = [&](int off) {
        half_t* base = SMEM + off;
        async16(base + wv * 512,              gA0);
        async16(base + (4 + wv) * 512,        gA1);
        async16(base + 4096 + wv * 512,       gB0);
        async16(base + 4096 + (4 + wv) * 512, gB1);
        gA0 += 32; gA1 += 32; gB0 += 32; gB1 += 32;
    };
    // fragment read: granule = l15*4 + (q ^ ((l15>>2)&3)) within g-block (wm*4+mi / wn*4+ni)
    auto compute = [&](int off) {
        const half_t* Asb = SMEM + off;
        const half_t* Bsb = Asb + 4096;
        const int sw = (q ^ ((l15 >> 2) & 3)) * 8 + l15 * 32;
        h8 af[4], bf[4];
        #pragma unroll
        for (int mi = 0; mi < 4; ++mi) af[mi] = *(const h8*)(Asb + (wm * 4 + mi) * 512 + sw);
        #pragma unroll
        for (int ni = 0; ni < 4; ++ni) bf[ni] = *(const h8*)(Bsb + (wn * 4 + ni) * 512 + sw);
        #pragma unroll
        for (int mi = 0; mi < 4; ++mi)
            #pragma unroll
            for (int ni = 0; ni < 4; ++ni)
                acc[mi][ni] = __builtin_amdgcn_mfma_f32_16x16x32_f16(af[mi], bf[ni], acc[mi][ni], 0, 0, 0);
    };

    stage(0);
    __syncthreads();
    for (int kt = 0; kt < nKt; kt += 2) {
        stage(8192);
        compute(0);
        __syncthreads();
        if (kt + 2 < nKt) stage(0);
        compute(8192);
        __syncthreads();
    }

    if (P.outMode[s] == 1) {
        half_t* Cz = (half_t*)P.C[s] + (long long)(z / P.divC[s]) * P.sChi[s] + (long long)(z % P.divC[s]) * P.sClo[s];
        #pragma unroll
        for (int mi = 0; mi < 4; ++mi)
            #pragma unroll
            for (int r = 0; r < 4; ++r) {
                const int row = m0 + wm * 64 + mi * 16 + q * 4 + r;
                if (row < Mlim) {
                    #pragma unroll
                    for (int ni = 0; ni < 4; ++ni) {
                        const int col = n0 + wn * 64 + ni * 16 + l15;
                        if (col < Nlim) Cz[(long long)row * ldc + col] = (half_t)(acc[mi][ni][r] * alpha);
                    }
                }
            }
    } else {
        // coalesced transpose epilogue: C[col][m], ldc-padded rows; pad-writes are garbage
        // that downstream consumers never read meaningfully (zero-masked A-columns).
        // Single pass through overlay T2[128 cols][128 m], h4-granule XOR swizzle.
        half_t (*T2)[128] = (half_t(*)[128])SMEM;
        half_t* Cz = (half_t*)P.C[s] + (long long)(z / P.divC[s]) * P.sChi[s] + (long long)(z % P.divC[s]) * P.sClo[s];
        #pragma unroll
        for (int mi = 0; mi < 4; ++mi)
            #pragma unroll
            for (int ni = 0; ni < 4; ++ni) {
                h4 pk;
                #pragma unroll
                for (int r = 0; r < 4; ++r) pk[r] = (half_t)(acc[mi][ni][r] * alpha);
                const int col = wn * 64 + ni * 16 + l15;
                const int g   = wm * 16 + mi * 4 + q;               // m-group (4 halves)
                *(h4*)&T2[col][4 * (g ^ (col & 31))] = pk;
            }
        __syncthreads();
        {
            const int col  = tid >> 1;
            const int coff = (tid & 1) * 64;
            const int gb   = (tid & 1) * 16;
            const int mbase = m0 + coff;
            const int nfull = max(0, min(64, ldc - mbase)) >> 3;    // whole h8 runs in-row
            if (n0 + col < Nlim && nfull > 0) {
                half_t* rp = Cz + (long long)(n0 + col) * ldc + mbase;
                for (int j = 0; j < nfull; ++j) {
                    h4 lo = *(h4*)&T2[col][4 * ((gb + 2 * j)     ^ (col & 31))];
                    h4 hi = *(h4*)&T2[col][4 * ((gb + 2 * j + 1) ^ (col & 31))];
                    h8 v = {lo[0], lo[1], lo[2], lo[3], hi[0], hi[1], hi[2], hi[3]};
                    *(h8*)(rp + j * 8) = v;
                }
            }
        }
    }
}

// ---------------- scores: A-strip-resident GEMM + fused IN-stat partials ----------------
// B = KT[h][960][3200] (global-n rows, pad cols garbage — masked by zero A-columns).
// z enumerated h-major so co-XCD blocks share a head: their KT windows are adjacent
// column ranges of the SAME rows -> full line utilization, ~3 MB/XCD L2 footprint.
struct ScP {
    const half_t* Qt[4];
    const half_t* KT;
    half_t* C[4];
    float* Part[4];
    int Mlim[4];
    long long sA[4], sC[4];
    float alpha;
};

__global__ __launch_bounds__(256)
void gemm_s(ScP P)
{
    __shared__ __align__(16) half_t As[128][232];   // full-K strip (196 -> zero-pad)
    __shared__ __align__(16) half_t Bs[128][72];    // 64-wide B chunk
    __shared__ float red[8];

    const int per = gridDim.x >> 3;                 // 512/8 = 64 -> 8 z per XCD
    int wk = (blockIdx.x & 7) * per + (blockIdx.x >> 3);
    const int zl = wk >> 3, r = wk & 7;
    int s, mt;
    if (r < 1)      { s = 0; mt = 0; }
    else if (r < 2) { s = 1; mt = 0; }
    else if (r < 4) { s = 2; mt = r - 2; }
    else            { s = 3; mt = r - 4; }
    const int h = zl >> 4, b = zl & 15;             // h-major enumeration
    const int zq = b * 4 + h;                       // storage order of Qt/C/Part planes

    const half_t* A = P.Qt[s] + (long long)zq * P.sA[s] + (long long)mt * 128 * 208;
    const half_t* B = P.KT + (long long)h * 3072000 + (long long)b * 196;   // [960][3200] window
    const int rowLim = P.Mlim[s] - mt * 128;
    const float alpha = P.alpha;

    const int tid = threadIdx.x;
    const int lane = tid & 63, wv = tid >> 6;
    const int wm = wv & 1, wn = wv >> 1;
    const int l15 = lane & 15, q = lane >> 4;
    const int r0 = tid >> 2, kg = tid & 3;

    #pragma unroll
    for (int c = 0; c < 7; ++c) {
        const int kb = c * 32 + kg * 8;
        h8 a0 = ldtile(A, r0, kb, 208, rowLim, 196);
        h8 a1 = ldtile(A, r0 + 64, kb, 208, rowLim, 196);
        *(h8*)&As[r0][kb] = a0;
        *(h8*)&As[r0 + 64][kb] = a1;
    }

    half_t* Cz = P.C[s] + (long long)zq * P.sC[s] + (long long)mt * 128 * 960;
    float sv = 0.f, qq = 0.f;

    for (int nt = 0; nt < 8; ++nt) {
        f4v acc[4][4];
        #pragma unroll
        for (int i = 0; i < 4; ++i)
            #pragma unroll
            for (int j = 0; j < 4; ++j) acc[i][j] = (f4v){0.f, 0.f, 0.f, 0.f};

        const int j0 = nt * 128;
        #pragma unroll
        for (int c2 = 0; c2 < 4; ++c2) {
            h8 b00 = ldtile(B, j0 + r0,      c2 * 64 + kg * 8,      3200, 960, 196);
            h8 b01 = ldtile(B, j0 + r0,      c2 * 64 + 32 + kg * 8, 3200, 960, 196);
            h8 b10 = ldtile(B, j0 + r0 + 64, c2 * 64 + kg * 8,      3200, 960, 196);
            h8 b11 = ldtile(B, j0 + r0 + 64, c2 * 64 + 32 + kg * 8, 3200, 960, 196);
            __syncthreads();
            *(h8*)&Bs[r0][kg * 8] = b00;
            *(h8*)&Bs[r0][32 + kg * 8] = b01;
            *(h8*)&Bs[r0 + 64][kg * 8] = b10;
            *(h8*)&Bs[r0 + 64][32 + kg * 8] = b11;
            __syncthreads();
            const int nkk = (c2 < 3) ? 2 : 1;
            for (int kk = 0; kk < nkk; ++kk) {
                const int base = c2 * 64 + kk * 32;
                h8 af[4], bf[4];
                #pragma unroll
                for (int mi = 0; mi < 4; ++mi) af[mi] = *(h8*)&As[wm * 64 + mi * 16 + l15][base + q * 8];
                #pragma unroll
                for (int ni = 0; ni < 4; ++ni) bf[ni] = *(h8*)&Bs[wn * 64 + ni * 16 + l15][kk * 32 + q * 8];
                #pragma unroll
                for (int mi = 0; mi < 4; ++mi)
                    #pragma unroll
                    for (int ni = 0; ni < 4; ++ni)
                        acc[mi][ni] = __builtin_amdgcn_mfma_f32_16x16x32_f16(af[mi], bf[ni], acc[mi][ni], 0, 0, 0);
            }
        }
        #pragma unroll
        for (int mi = 0; mi < 4; ++mi)
            #pragma unroll
            for (int rr = 0; rr < 4; ++rr) {
                const int rowl = wm * 64 + mi * 16 + q * 4 + rr;
                #pragma unroll
                for (int ni = 0; ni < 4; ++ni) {
                    const int col = j0 + wn * 64 + ni * 16 + l15;
                    const float v = acc[mi][ni][rr] * alpha;
                    sv += v; qq += v * v;
                    if (rowl < rowLim && col < 960)
                        Cz[(long long)rowl * 960 + col] = (half_t)v;
                }
            }
    }

    #pragma unroll
    for (int o = 32; o > 0; o >>= 1) {
        sv += __shfl_down(sv, o, 64);
        qq += __shfl_down(qq, o, 64);
    }
    if (lane == 0) { red[wv] = sv; red[4 + wv] = qq; }
    __syncthreads();
    if (tid == 0) {
        float* PO = P.Part[s] + (long long)zq * 240 + mt * 2;
        PO[0] = red[0] + red[1] + red[2] + red[3];
        PO[1] = red[4] + red[5] + red[6] + red[7];
    }
}

// ---------------- ctx: fused IN-scale + exp + PV GEMM + denominator normalize ----------------
struct CtxP {
    const half_t* V;
    const half_t* S[4];
    half_t* C[4];
    const float* Part[4];
    int ch[4];
    int nPart[4];
    float pinv[4];
};

__global__ __launch_bounds__(256)
void ctx_k(CtxP P)
{
    __shared__ __align__(16) half_t As[128][40];
    __shared__ __align__(16) half_t Bs[128][40];
    __shared__ float denomP[128][4];
    __shared__ float denom[128];

    const int per = gridDim.x >> 3;                 // 1024/8 = 128 -> 8 z per XCD
    int wk = (blockIdx.x & 7) * per + (blockIdx.x >> 3);
    const int z = wk >> 4;
    const int r = wk & 15;
    int s, mt, nt;
    if (r < 2)      { s = 0; mt = r;            nt = 0; }
    else if (r < 4) { s = 1; mt = r - 2;        nt = 0; }
    else if (r < 8) { s = 2; mt = (r - 4) >> 1; nt = (r - 4) & 1; }
    else            { s = 3; mt = (r - 8) >> 2; nt = (r - 8) & 3; }
    const int b = z >> 2, h = z & 3;
    const int chS = P.ch[s];

    const float* part = P.Part[s] + (long long)z * 240;
    float Ssum = 0.f, Qsum = 0.f;
    for (int i = 0; i < P.nPart[s]; ++i) { Ssum += part[i * 2]; Qsum += part[i * 2 + 1]; }
    const float mn = Ssum * P.pinv[s];
    const float rs = rsqrtf(fmaxf(Qsum * P.pinv[s] - mn * mn, 0.f) + 1e-5f);

    const half_t* Av  = P.V + (long long)h * 3010560 + (long long)b * 188160;   // [196][960]
    const half_t* Bsc = P.S[s] + (long long)z * 960 * chS;                      // [ch][960] raw
    const int m0 = mt * 128, n0 = nt * 128;

    const int tid = threadIdx.x;
    const int lane = tid & 63, wv = tid >> 6;
    const int wm = wv & 1, wn = wv >> 1;
    const int l15 = lane & 15, q = lane >> 4;
    const int r0 = tid >> 2, kg = tid & 3;
    const int d0 = n0 + r0, d1 = n0 + r0 + 64;
    const bool ok0 = d0 < chS, ok1 = d1 < chS;

    f4v acc[4][4];
    #pragma unroll
    for (int i = 0; i < 4; ++i)
        #pragma unroll
        for (int j = 0; j < 4; ++j) acc[i][j] = (f4v){0.f, 0.f, 0.f, 0.f};

    float ds0 = 0.f, ds1 = 0.f;

    // prologue: loads for kt=0
    h8 a0n = ldtile(Av, m0 + r0, kg * 8, 960, 196, 960);
    h8 a1n = ldtile(Av, m0 + r0 + 64, kg * 8, 960, 196, 960);
    h8 s0n = {0,0,0,0,0,0,0,0}, s1n = {0,0,0,0,0,0,0,0};
    if (ok0) s0n = *(const h8*)(Bsc + (long long)d0 * 960 + kg * 8);
    if (ok1) s1n = *(const h8*)(Bsc + (long long)d1 * 960 + kg * 8);

    for (int kt = 0; kt < 30; ++kt) {
        h8 e0 = {0,0,0,0,0,0,0,0}, e1 = {0,0,0,0,0,0,0,0};
        if (ok0) {
            #pragma unroll
            for (int e = 0; e < 8; ++e) { float ev = __expf((float)s0n[e] * rs); ds0 += ev; e0[e] = (half_t)ev; }
        }
        if (ok1) {
            #pragma unroll
            for (int e = 0; e < 8; ++e) { float ev = __expf((float)s1n[e] * rs); ds1 += ev; e1[e] = (half_t)ev; }
        }
        h8 a0c = a0n, a1c = a1n;
        __syncthreads();
        *(h8*)&As[r0][kg * 8] = a0c;
        *(h8*)&As[r0 + 64][kg * 8] = a1c;
        *(h8*)&Bs[r0][kg * 8] = e0;
        *(h8*)&Bs[r0 + 64][kg * 8] = e1;
        __syncthreads();
        if (kt < 29) {
            const int kb = (kt + 1) * 32 + kg * 8;
            a0n = ldtile(Av, m0 + r0, kb, 960, 196, 960);
            a1n = ldtile(Av, m0 + r0 + 64, kb, 960, 196, 960);
            if (ok0) s0n = *(const h8*)(Bsc + (long long)d0 * 960 + kb);
            if (ok1) s1n = *(const h8*)(Bsc + (long long)d1 * 960 + kb);
        }
        h8 af[4], bf[4];
        #pragma unroll
        for (int mi = 0; mi < 4; ++mi) af[mi] = *(h8*)&As[wm * 64 + mi * 16 + l15][q * 8];
        #pragma unroll
        for (int ni = 0; ni < 4; ++ni) bf[ni] = *(h8*)&Bs[wn * 64 + ni * 16 + l15][q * 8];
        #pragma unroll
        for (int mi = 0; mi < 4; ++mi)
            #pragma unroll
            for (int ni = 0; ni < 4; ++ni)
                acc[mi][ni] = __builtin_amdgcn_mfma_f32_16x16x32_f16(af[mi], bf[ni], acc[mi][ni], 0, 0, 0);
    }

    denomP[r0][kg] = ds0;
    denomP[r0 + 64][kg] = ds1;
    __syncthreads();
    if (tid < 128) denom[tid] = denomP[tid][0] + denomP[tid][1] + denomP[tid][2] + denomP[tid][3];
    __syncthreads();

    half_t* Cz = P.C[s] + (long long)b * 784 * chS + (long long)h * chS;
    const int ldc = 4 * chS;
    #pragma unroll
    for (int ni = 0; ni < 4; ++ni) {
        const int coll = wn * 64 + ni * 16 + l15;
        const int col = n0 + coll;
        if (col < chS) {
            const float sc = 0.25f / denom[coll];
            #pragma unroll
            for (int mi = 0; mi < 4; ++mi)
                #pragma unroll
                for (int rr = 0; rr < 4; ++rr) {
                    const int row = m0 + wm * 64 + mi * 16 + q * 4 + rr;
                    if (row < 196)
                        Cz[(long long)row * ldc + col] = (half_t)(acc[mi][ni][rr] * sc);
                }
        }
    }
}

// ---------------- launcher ----------------
extern "C" void kernel_launch(void* const* d_in, const int* in_sizes, int n_in,
                              void* d_out, int out_size, void* d_ws, size_t ws_size,
                              hipStream_t stream)
{
    const float* emb[4]  = {(const float*)d_in[0], (const float*)d_in[1],
                            (const float*)d_in[2], (const float*)d_in[3]};
    const float* emb_all = (const float*)d_in[4];
    const float* Wq[4]   = {(const float*)d_in[5], (const float*)d_in[7],
                            (const float*)d_in[9], (const float*)d_in[11]};
    const float* Wo[4]   = {(const float*)d_in[6], (const float*)d_in[8],
                            (const float*)d_in[10], (const float*)d_in[12]};
    const float* Wk = (const float*)d_in[13];
    const float* Wv = (const float*)d_in[14];
    float* out = (float*)d_out;

    half_t* hb = (half_t*)d_ws;
    half_t* EAh = hb;                              // 3010560
    half_t* Eh  = EAh + 3010560;                   // 3010560
    half_t* Wkh = Eh  + 3010560;                   // 3686400
    half_t* Wvh = Wkh + 3686400;                   // 3686400
    half_t* Wqh = Wvh + 3686400;                   // 1392640
    half_t* Wo4 = Wqh + 1392640;                   // 1392640
    half_t* KT  = Wo4 + 1392640;                   // [h][960][3200]        = 12288000 (slot 12779520)
    half_t* Vh  = KT  + 12779520;                  // [h][3136][960]        = 12042240
    half_t* QtT = Vh  + 12042240;                  // per-scale [64][ch][208] = 12779520
    half_t* Ctx = QtT + 12779520;                  // per-scale [16][196][4ch] = 12042240
    half_t* Sch = Ctx + 12042240;                  // per-scale [64][ch][960] raw = 58982400
    float*  Part = (float*)(Sch + 58982400);       // 4 * 64 * 240 floats

    const int  chs[4]   = {64, 128, 256, 512};
    const int  lg2c[4]  = {6, 7, 8, 9};
    const long long offE[4]   = {0, 200704, 602112, 1404928};
    const long long offQ[4]   = {0, 16384, 81920, 344064};
    const long long offQt[4]  = {0, 851968, 2555904, 5963776};
    const long long offSc[4]  = {0, 3932160, 11796480, 27525120};
    const long long offCtx[4] = {0, 802816, 2408448, 5619712};
    const long long ooff[4]   = {0, 200704, 602112, 1404928};
    const float inv_sqrt_kv = 0.03227486121839514f;

    // ---- prep ----
    PrepArgs pa;
    pa.src[0] = emb_all; pa.dst[0] = EAh; pa.n[0] = 3010560; pa.mode[0] = 0; pa.lg2[0] = 0;
    for (int i = 0; i < 4; ++i) {
        pa.src[1 + i] = emb[i]; pa.dst[1 + i] = Eh + offE[i];
        pa.n[1 + i] = (int)(3136LL * chs[i]); pa.mode[1 + i] = 0; pa.lg2[1 + i] = 0;
    }
    pa.src[5] = Wk; pa.dst[5] = Wkh; pa.n[5] = 3686400; pa.mode[5] = 0; pa.lg2[5] = 0;
    pa.src[6] = Wv; pa.dst[6] = Wvh; pa.n[6] = 3686400; pa.mode[6] = 0; pa.lg2[6] = 0;
    for (int i = 0; i < 4; ++i) {
        pa.src[7 + i] = Wq[i]; pa.dst[7 + i] = Wqh + offQ[i];
        pa.n[7 + i] = 4 * chs[i] * chs[i]; pa.mode[7 + i] = 0; pa.lg2[7 + i] = 0;
        pa.src[11 + i] = Wo[i]; pa.dst[11 + i] = Wo4 + offQ[i];
        pa.n[11 + i] = chs[i] * chs[i]; pa.mode[11 + i] = 1; pa.lg2[11 + i] = lg2c[i];
    }
    prep_k<<<dim3(1800, 15), 256, 0, stream>>>(pa);

    // ---- K-proj + V-proj + Q-proj (all scales) in ONE 128x128 launch ----
    {
        BP p{};
        // slot 0: K projection -> KT[h][col j][n 3200] (transposed, coalesced runs)
        p.A[0] = EAh; p.B[0] = Wkh; p.C[0] = KT;
        p.Mlim[0] = 3136; p.Nlim[0] = 960; p.Klim[0] = 960; p.nKt[0] = 30;
        p.lda[0] = 960; p.ldb[0] = 960; p.ldc[0] = 3200;
        p.divA[0] = 1; p.sAhi[0] = 0; p.sAlo[0] = 0;
        p.divB[0] = 1; p.sBhi[0] = 921600; p.sBlo[0] = 0;
        p.divC[0] = 1; p.sChi[0] = 3072000; p.sClo[0] = 0;
        p.outMode[0] = 2; p.alpha[0] = 1.0f;
        p.mT[0] = 25; p.nT[0] = 8;
        // slot 1: V projection -> Vh[h][3136][960] (normal)
        p.A[1] = EAh; p.B[1] = Wvh; p.C[1] = Vh;
        p.Mlim[1] = 3136; p.Nlim[1] = 960; p.Klim[1] = 960; p.nKt[1] = 30;
        p.lda[1] = 960; p.ldb[1] = 960; p.ldc[1] = 960;
        p.divA[1] = 1; p.sAhi[1] = 0; p.sAlo[1] = 0;
        p.divB[1] = 1; p.sBhi[1] = 921600; p.sBlo[1] = 0;
        p.divC[1] = 1; p.sChi[1] = 3010560; p.sClo[1] = 0;
        p.outMode[1] = 1; p.alpha[1] = 1.0f;
        p.mT[1] = 25; p.nT[1] = 8;
        // slots 2..5: Q-proj per scale -> QtT[z][d][208] (transposed, coalesced runs)
        for (int i = 0; i < 4; ++i) {
            const int sl = 2 + i, ch = chs[i];
            p.A[sl] = Eh + offE[i]; p.B[sl] = Wqh + offQ[i]; p.C[sl] = QtT + offQt[i];
            p.Mlim[sl] = 196; p.Nlim[sl] = ch; p.Klim[sl] = ch; p.nKt[sl] = ch / 32;
            p.lda[sl] = ch; p.ldb[sl] = ch; p.ldc[sl] = 208;
            p.divA[sl] = 4; p.sAhi[sl] = 196LL * ch; p.sAlo[sl] = 0;
            p.divB[sl] = 4; p.sBhi[sl] = 0; p.sBlo[sl] = (long long)ch * ch;
            p.divC[sl] = 1; p.sChi[sl] = 208LL * ch; p.sClo[sl] = 0;
            p.outMode[sl] = 2; p.alpha[sl] = 1.0f;
            p.mT[sl] = 2; p.nT[sl] = (ch + 127) / 128;
        }
        int cum = 0;
        const int blocks[6] = {800, 800, 128, 128, 256, 512};
        for (int sl = 0; sl < 6; ++sl) { cum += blocks[sl]; if (sl < 5) p.cumEnd[sl] = cum; }
        p.totW = cum;                       // 2624, divisible by 8; every segment divisible by 8
        gemm_w<<<2624, 256, 0, stream>>>(p);
    }

    // ---- Scores (raw) + stats, strip-resident ----
    {
        ScP p{};
        for (int s = 0; s < 4; ++s) {
            p.Qt[s] = QtT + offQt[s];
            p.C[s] = Sch + offSc[s];
            p.Part[s] = Part + (long long)s * 64 * 240;
            p.Mlim[s] = chs[s];
            p.sA[s] = 208LL * chs[s];
            p.sC[s] = 960LL * chs[s];
        }
        p.KT = KT;
        p.alpha = inv_sqrt_kv;
        gemm_s<<<512, 256, 0, stream>>>(p);
    }

    // ---- ctx: fused exp/softmax + PV (pipelined) ----
    {
        CtxP p{};
        p.V = Vh;
        const int nP[4] = {1, 1, 2, 4};
        for (int s = 0; s < 4; ++s) {
            p.S[s] = Sch + offSc[s];
            p.C[s] = Ctx + offCtx[s];
            p.Part[s] = Part + (long long)s * 64 * 240;
            p.ch[s] = chs[s];
            p.nPart[s] = nP[s];
            p.pinv[s] = 1.0f / (chs[s] * 960);
        }
        ctx_k<<<1024, 256, 0, stream>>>(p);
    }

    // ---- out-proj, all scales: out fp32 = Ctx (196 x 4ch) x Wo4^T (64x64) ----
    {
        BP p{};
        int cum = 0;
        for (int s = 0; s < 4; ++s) {
            const int ch = chs[s];
            p.A[s] = Ctx + offCtx[s]; p.B[s] = Wo4 + offQ[s]; p.C[s] = out + ooff[s];
            p.Mlim[s] = 196; p.Nlim[s] = ch; p.Klim[s] = 4 * ch; p.nKt[s] = ch / 8;
            p.lda[s] = 4 * ch; p.ldb[s] = 4 * ch; p.ldc[s] = ch;
            p.divA[s] = 1; p.sAhi[s] = 784LL * ch; p.sAlo[s] = 0;
            p.divB[s] = 1; p.sBhi[s] = 0; p.sBlo[s] = 0;
            p.divC[s] = 1; p.sChi[s] = 196LL * ch; p.sClo[s] = 0;
            p.outMode[s] = 0; p.alpha[s] = 1.0f;
            p.mT[s] = 4; p.nT[s] = ch / 64;
            cum += 4 * (ch / 64) * 16;
            if (s < 3) p.cumEnd[s] = cum;
        }
        p.cumEnd[3] = p.cumEnd[4] = cum;
        p.totW = cum;
        gemm_b<<<960, 128, 0, stream>>>(p);
    }
}